// Round 1
// baseline (1559.857 us; speedup 1.0000x reference)
//
#include <hip/hip_runtime.h>
#include <math.h>

#define LSEQ 16384
#define DM 192
#define DI 384
#define DSN 16
#define DCONV 4
#define DTRK 12
#define NPROJ 44   /* DTRK + 2*DSN */
#define EPSV 1e-5f
#define TCH 128
#define NCH (LSEQ / TCH)

__device__ __forceinline__ float siluf(float x) { return x / (1.f + __expf(-x)); }
__device__ __forceinline__ float softplusf(float x) { return (x > 20.f) ? x : log1pf(__expf(x)); }

// ---------------- out = x ----------------
__global__ void k_copy_out(const float* __restrict__ x, float* __restrict__ o, int n) {
  int i = blockIdx.x * 256 + threadIdx.x;
  if (i < n) o[i] = x[i];
}

// ---------------- fold norm weight into in_proj (192x768) ----------------
__global__ void k_fold(const float* __restrict__ Wi, const float* __restrict__ nw,
                       float* __restrict__ Wc) {
  int i = blockIdx.x * 256 + threadIdx.x;
  if (i >= DM * 768) return;
  int k = i / 768;
  Wc[i] = nw[k] * Wi[i];
}

// ---------------- gather + rmsnorm (weightless; weight folded) ----------------
__global__ __launch_bounds__(64) void k_gather_rms(const float* __restrict__ x,
                                                   const int* __restrict__ idx,
                                                   float* __restrict__ xon) {
  int t = blockIdx.x;
  int lane = threadIdx.x;
  int r = idx[t];
  float v0 = x[(size_t)r*DM + lane];
  float v1 = x[(size_t)r*DM + 64 + lane];
  float v2 = x[(size_t)r*DM + 128 + lane];
  float ss = v0*v0 + v1*v1 + v2*v2;
  #pragma unroll
  for (int o = 32; o > 0; o >>= 1) ss += __shfl_xor(ss, o);
  float s = rsqrtf(ss * (1.f/DM) + EPSV);
  xon[(size_t)t*DM + lane]       = v0 * s;
  xon[(size_t)t*DM + 64 + lane]  = v1 * s;
  xon[(size_t)t*DM + 128 + lane] = v2 * s;
}

// ---------------- generic f32 GEMM: C(MxN) = A(MxK) @ B(KxN) ----------------
// 64x64 tile, 256 threads, 4x4 per thread. K % 16 == 0, M % 64 == 0. N guarded.
__global__ __launch_bounds__(256) void k_gemm(const float* __restrict__ A,
                                              const float* __restrict__ B,
                                              float* __restrict__ C,
                                              int M, int N, int K) {
  __shared__ float As[16][68];   // +4 pad: breaks 16-way store conflict
  __shared__ float Bs[16][64];
  int bm = blockIdx.y * 64, bn = blockIdx.x * 64;
  int tid = threadIdx.x;
  int tx = tid & 15, ty = tid >> 4;
  float acc[4][4] = {};
  for (int k0 = 0; k0 < K; k0 += 16) {
    int ka = tid & 15, ma = tid >> 4;
    #pragma unroll
    for (int i = 0; i < 4; i++)
      As[ka][ma + 16*i] = A[(size_t)(bm + ma + 16*i) * K + k0 + ka];
    int nb = tid & 63, kb = tid >> 6;
    #pragma unroll
    for (int i = 0; i < 4; i++) {
      int kk = kb + 4*i;
      Bs[kk][nb] = (bn + nb < N) ? B[(size_t)(k0 + kk) * N + bn + nb] : 0.f;
    }
    __syncthreads();
    #pragma unroll
    for (int k = 0; k < 16; k++) {
      float a[4], b[4];
      #pragma unroll
      for (int i = 0; i < 4; i++) a[i] = As[k][ty*4 + i];
      #pragma unroll
      for (int j = 0; j < 4; j++) b[j] = Bs[k][tx*4 + j];
      #pragma unroll
      for (int i = 0; i < 4; i++)
        #pragma unroll
        for (int j = 0; j < 4; j++)
          acc[i][j] += a[i] * b[j];
    }
    __syncthreads();
  }
  #pragma unroll
  for (int i = 0; i < 4; i++) {
    int m = bm + ty*4 + i;
    #pragma unroll
    for (int j = 0; j < 4; j++) {
      int n = bn + tx*4 + j;
      if (n < N) C[(size_t)m * N + n] = acc[i][j];
    }
  }
}

// ---------------- out-proj GEMM with fused A = y * silu(z) ----------------
// A[m][k] = XZ[m*768 + k] * silu(XZ[m*768 + 384 + k]);  B = Wo (384x192)
__global__ __launch_bounds__(256) void k_gemm_yz(const float* __restrict__ XZ,
                                                 const float* __restrict__ B,
                                                 float* __restrict__ C,
                                                 int M, int N, int K) {
  __shared__ float As[16][68];
  __shared__ float Bs[16][64];
  int bm = blockIdx.y * 64, bn = blockIdx.x * 64;
  int tid = threadIdx.x;
  int tx = tid & 15, ty = tid >> 4;
  float acc[4][4] = {};
  for (int k0 = 0; k0 < K; k0 += 16) {
    int ka = tid & 15, ma = tid >> 4;
    #pragma unroll
    for (int i = 0; i < 4; i++) {
      size_t row = (size_t)(bm + ma + 16*i) * 768;
      float yv = XZ[row + k0 + ka];
      float zv = XZ[row + 384 + k0 + ka];
      As[ka][ma + 16*i] = yv * siluf(zv);
    }
    int nb = tid & 63, kb = tid >> 6;
    #pragma unroll
    for (int i = 0; i < 4; i++) {
      int kk = kb + 4*i;
      Bs[kk][nb] = (bn + nb < N) ? B[(size_t)(k0 + kk) * N + bn + nb] : 0.f;
    }
    __syncthreads();
    #pragma unroll
    for (int k = 0; k < 16; k++) {
      float a[4], b[4];
      #pragma unroll
      for (int i = 0; i < 4; i++) a[i] = As[k][ty*4 + i];
      #pragma unroll
      for (int j = 0; j < 4; j++) b[j] = Bs[k][tx*4 + j];
      #pragma unroll
      for (int i = 0; i < 4; i++)
        #pragma unroll
        for (int j = 0; j < 4; j++)
          acc[i][j] += a[i] * b[j];
    }
    __syncthreads();
  }
  #pragma unroll
  for (int i = 0; i < 4; i++) {
    int m = bm + ty*4 + i;
    #pragma unroll
    for (int j = 0; j < 4; j++) {
      int n = bn + tx*4 + j;
      if (n < N) C[(size_t)m * N + n] = acc[i][j];
    }
  }
}

// ---------------- causal depthwise conv + silu ----------------
// sgn=+1: y[t] = b + sum_k w[k]*xc[t-3+k];  sgn=-1: y[t] = b + sum_k w[k]*xc[t+3-k]
__global__ void k_conv(const float* __restrict__ XZ, int sgn,
                       const float* __restrict__ cw, const float* __restrict__ cb,
                       float* __restrict__ U) {
  int i = blockIdx.x * 256 + threadIdx.x;
  if (i >= LSEQ * DI) return;
  int t = i / DI, d = i % DI;
  float acc = cb[d];
  #pragma unroll
  for (int k = 0; k < DCONV; k++) {
    int r = (sgn > 0) ? (t - (DCONV-1) + k) : (t + (DCONV-1) - k);
    if (r >= 0 && r < LSEQ) acc += cw[d*DCONV + k] * XZ[(size_t)r*768 + d];
  }
  U[i] = siluf(acc);
}

// ---------------- dt = softplus(proj[:, :12] @ Wdt + bdt) ----------------
__global__ __launch_bounds__(384) void k_dt(const float* __restrict__ P,
                                            const float* __restrict__ Wdt,
                                            const float* __restrict__ bdt,
                                            float* __restrict__ DT) {
  __shared__ float pr[DTRK];
  int t = blockIdx.x, d = threadIdx.x;
  if (d < DTRK) pr[d] = P[(size_t)t*NPROJ + d];
  __syncthreads();
  float acc = bdt[d];
  #pragma unroll
  for (int k = 0; k < DTRK; k++) acc += pr[k] * Wdt[k*DI + d];
  DT[(size_t)t*DI + d] = softplusf(acc);
}

// ---------------- scan phase 1: per-chunk local scan + chunk product ----------------
__global__ __launch_bounds__(128) void k_scan1(const float* __restrict__ DT,
                                               const float* __restrict__ U,
                                               const float* __restrict__ PROJ,
                                               const float* __restrict__ Alog,
                                               int sgn,
                                               float* __restrict__ Pc,
                                               float* __restrict__ Sc) {
  __shared__ float Bs[TCH][DSN];
  int c = blockIdx.y;
  int d = blockIdx.x * 128 + threadIdx.x;
  for (int i = threadIdx.x; i < TCH*DSN; i += 128) {
    int t = i >> 4, n = i & 15;
    int tt = c*TCH + t;
    int row = (sgn > 0) ? tt : (LSEQ-1-tt);
    Bs[t][n] = PROJ[(size_t)row*NPROJ + DTRK + n];
  }
  __syncthreads();
  float A[DSN], S[DSN];
  #pragma unroll
  for (int n = 0; n < DSN; n++) { A[n] = -__expf(Alog[d*DSN + n]); S[n] = 0.f; }
  float dtsum = 0.f;
  for (int t = 0; t < TCH; t++) {
    int tt = c*TCH + t;
    int row = (sgn > 0) ? tt : (LSEQ-1-tt);
    float dtv = DT[(size_t)row*DI + d];
    float du  = dtv * U[(size_t)row*DI + d];
    dtsum += dtv;
    #pragma unroll
    for (int n = 0; n < DSN; n++) {
      float a = __expf(dtv * A[n]);
      S[n] = a * S[n] + du * Bs[t][n];
    }
  }
  size_t base = (size_t)c * (DI*DSN) + (size_t)d * DSN;
  #pragma unroll
  for (int n = 0; n < DSN; n++) {
    Pc[base + n] = __expf(A[n] * dtsum);
    Sc[base + n] = S[n];
  }
}

// ---------------- scan phase 2: sequential over chunk summaries ----------------
__global__ void k_scan2(const float* __restrict__ Pc, const float* __restrict__ Sc,
                        float* __restrict__ Hc) {
  int g = blockIdx.x * blockDim.x + threadIdx.x;  // 6144 = DI*DSN
  float H = 0.f;
  for (int c = 0; c < NCH; c++) {
    size_t o = (size_t)c * (DI*DSN) + g;
    Hc[o] = H;
    H = Pc[o] * H + Sc[o];
  }
}

// ---------------- scan phase 3: rescan with init state, emit y into xz col 0 ----------------
__global__ __launch_bounds__(128) void k_scan3(const float* __restrict__ DT,
                                               const float* __restrict__ U,
                                               const float* __restrict__ PROJ,
                                               const float* __restrict__ Alog,
                                               const float* __restrict__ Dp,
                                               const float* __restrict__ Hc,
                                               int sgn,
                                               float* __restrict__ Y /* xz, ld 768 */) {
  __shared__ float Bs[TCH][DSN];
  __shared__ float Cs[TCH][DSN];
  int c = blockIdx.y;
  int d = blockIdx.x * 128 + threadIdx.x;
  for (int i = threadIdx.x; i < TCH*DSN; i += 128) {
    int t = i >> 4, n = i & 15;
    int tt = c*TCH + t;
    int row = (sgn > 0) ? tt : (LSEQ-1-tt);
    Bs[t][n] = PROJ[(size_t)row*NPROJ + DTRK + n];
    Cs[t][n] = PROJ[(size_t)row*NPROJ + DTRK + DSN + n];
  }
  __syncthreads();
  float A[DSN], h[DSN];
  size_t hb = (size_t)c*(DI*DSN) + (size_t)d*DSN;
  #pragma unroll
  for (int n = 0; n < DSN; n++) { A[n] = -__expf(Alog[d*DSN+n]); h[n] = Hc[hb+n]; }
  float dskip = Dp[d];
  for (int t = 0; t < TCH; t++) {
    int tt = c*TCH + t;
    int row = (sgn > 0) ? tt : (LSEQ-1-tt);
    float dtv = DT[(size_t)row*DI + d];
    float uv  = U[(size_t)row*DI + d];
    float du = dtv * uv;
    float y = uv * dskip;
    #pragma unroll
    for (int n = 0; n < DSN; n++) {
      float a = __expf(dtv * A[n]);
      h[n] = a * h[n] + du * Bs[t][n];
      y += h[n] * Cs[t][n];
    }
    Y[(size_t)row * 768 + d] = y;
  }
}

// ---------------- final: res+g4 -> LN_f + LN_b -> LN_out -> scatter-add ----------------
__device__ __forceinline__ void ln_row(float (&v)[3], const float* __restrict__ w,
                                       const float* __restrict__ b, int lane) {
  float s = v[0] + v[1] + v[2];
  #pragma unroll
  for (int o = 32; o > 0; o >>= 1) s += __shfl_xor(s, o);
  float m = s * (1.f / DM);
  float q = 0.f;
  #pragma unroll
  for (int i = 0; i < 3; i++) { float d = v[i] - m; q += d*d; }
  #pragma unroll
  for (int o = 32; o > 0; o >>= 1) q += __shfl_xor(q, o);
  float inv = rsqrtf(q * (1.f / DM) + EPSV);
  #pragma unroll
  for (int i = 0; i < 3; i++) v[i] = (v[i] - m) * inv * w[lane + 64*i] + b[lane + 64*i];
}

__global__ __launch_bounds__(64) void k_final(const float* __restrict__ x,
                                              const int* __restrict__ idx,
                                              const float* __restrict__ G4f,
                                              const float* __restrict__ G4b,
                                              const float* __restrict__ lnfw,
                                              const float* __restrict__ lnfb,
                                              const float* __restrict__ lnbw,
                                              const float* __restrict__ lnbb,
                                              const float* __restrict__ lnow,
                                              const float* __restrict__ lnob,
                                              float* __restrict__ out) {
  int t = blockIdx.x, lane = threadIdx.x;
  int r = idx[t];
  float f[3], g[3], cb[3];
  #pragma unroll
  for (int i = 0; i < 3; i++) {
    int j = lane + 64*i;
    float xo = x[(size_t)r*DM + j];
    f[i] = xo + G4f[(size_t)t*DM + j];
    g[i] = xo + G4b[(size_t)t*DM + j];
  }
  ln_row(f, lnfw, lnfb, lane);
  ln_row(g, lnbw, lnbb, lane);
  #pragma unroll
  for (int i = 0; i < 3; i++) cb[i] = f[i] + g[i];
  ln_row(cb, lnow, lnob, lane);
  #pragma unroll
  for (int i = 0; i < 3; i++) {
    int j = lane + 64*i;
    out[(size_t)r*DM + j] += cb[i];
  }
}

extern "C" void kernel_launch(void* const* d_in, const int* in_sizes, int n_in,
                              void* d_out, int out_size, void* d_ws, size_t ws_size,
                              hipStream_t stream) {
  const float* x      = (const float*)d_in[0];
  const int*   orders = (const int*)  d_in[1];
  const float* nw     = (const float*)d_in[2];
  const float* Wi     = (const float*)d_in[3];
  const float* cw     = (const float*)d_in[4];
  const float* cbi    = (const float*)d_in[5];
  const float* Wx     = (const float*)d_in[6];
  const float* Wdt    = (const float*)d_in[7];
  const float* bdt    = (const float*)d_in[8];
  const float* Alog   = (const float*)d_in[9];
  const float* Dp     = (const float*)d_in[10];
  const float* Wo     = (const float*)d_in[11];
  const float* flw    = (const float*)d_in[12];
  const float* flb    = (const float*)d_in[13];
  const float* blw    = (const float*)d_in[14];
  const float* blb    = (const float*)d_in[15];
  const float* olw    = (const float*)d_in[16];
  const float* olb    = (const float*)d_in[17];
  float* outp = (float*)d_out;

  // workspace carve-up (~152 MB total)
  char* w = (char*)d_ws;
  size_t off = 0;
  auto take = [&](size_t bytes) {
    char* p = w + off;
    off += (bytes + 255) & ~(size_t)255;
    return (float*)p;
  };
  float* Wc   = take((size_t)DM * 768 * 4);
  float* xon  = take((size_t)LSEQ * DM * 4);
  float* xz   = take((size_t)LSEQ * 768 * 4);
  float* uc   = take((size_t)LSEQ * DI * 4);
  float* proj = take((size_t)LSEQ * NPROJ * 4);
  float* dtf  = take((size_t)LSEQ * DI * 4);   // later reused as g4f (L x 192)
  float* dtb  = take((size_t)LSEQ * DI * 4);   // later reused as g4b (L x 192)
  float* Pc   = take((size_t)NCH * DI * DSN * 4);
  float* Sc   = take((size_t)NCH * DI * DSN * 4);
  float* Hc   = take((size_t)NCH * DI * DSN * 4);
  (void)ws_size; (void)n_in; (void)in_sizes; (void)out_size;

  k_copy_out<<<(LSEQ*DM + 255)/256, 256, 0, stream>>>(x, outp, LSEQ*DM);

  for (int o = 0; o < 2; o++) {
    const int* idx = orders + (size_t)o * LSEQ;
    k_gather_rms<<<LSEQ, 64, 0, stream>>>(x, idx, xon);

    for (int dir = 0; dir < 2; dir++) {
      int blk = (dir == 0) ? o : 2 + o;
      int sgn = (dir == 0) ? 1 : -1;
      float* dtbuf = (dir == 0) ? dtf : dtb;    // dt during scan, g4 after

      k_fold<<<(DM*768 + 255)/256, 256, 0, stream>>>(
          Wi + (size_t)blk*DM*768, nw + (size_t)blk*DM, Wc);
      k_gemm<<<dim3(768/64, LSEQ/64), 256, 0, stream>>>(xon, Wc, xz, LSEQ, 768, DM);
      k_conv<<<(LSEQ*DI + 255)/256, 256, 0, stream>>>(
          xz, sgn, cw + (size_t)blk*DI*DCONV, cbi + (size_t)blk*DI, uc);
      k_gemm<<<dim3(1, LSEQ/64), 256, 0, stream>>>(
          uc, Wx + (size_t)blk*DI*NPROJ, proj, LSEQ, NPROJ, DI);
      k_dt<<<LSEQ, DI, 0, stream>>>(
          proj, Wdt + (size_t)blk*DTRK*DI, bdt + (size_t)blk*DI, dtbuf);
      k_scan1<<<dim3(DI/128, NCH), 128, 0, stream>>>(
          dtbuf, uc, proj, Alog + (size_t)blk*DI*DSN, sgn, Pc, Sc);
      k_scan2<<<(DI*DSN)/256, 256, 0, stream>>>(Pc, Sc, Hc);
      k_scan3<<<dim3(DI/128, NCH), 128, 0, stream>>>(
          dtbuf, uc, proj, Alog + (size_t)blk*DI*DSN, Dp + (size_t)blk*DI, Hc, sgn, xz);
      // g4 = (y * silu(z)) @ Wo  -> overwrite dt buffer (dead after scan3)
      k_gemm_yz<<<dim3(DM/64, LSEQ/64), 256, 0, stream>>>(
          xz, Wo + (size_t)blk*DI*DM, dtbuf, LSEQ, DM, DI);
    }
    k_final<<<LSEQ, 64, 0, stream>>>(x, idx, dtf, dtb,
        flw + (size_t)o*DM, flb + (size_t)o*DM,
        blw + (size_t)o*DM, blb + (size_t)o*DM,
        olw + (size_t)o*DM, olb + (size_t)o*DM, outp);
  }
}

// Round 2
// 1133.547 us; speedup vs baseline: 1.3761x; 1.3761x over previous
//
#include <hip/hip_runtime.h>
#include <math.h>

#define LSEQ 16384
#define DM 192
#define DI 384
#define DSN 16
#define DCONV 4
#define DTRK 12
#define NPROJ 44   /* DTRK + 2*DSN */
#define EPSV 1e-5f
#define TCH 128
#define NCH (LSEQ / TCH)

typedef __attribute__((ext_vector_type(8))) short bf16x8;
typedef __attribute__((ext_vector_type(4))) float f32x4;

__device__ __forceinline__ float siluf(float x) { return x / (1.f + __expf(-x)); }
__device__ __forceinline__ float softplusf(float x) { return (x > 20.f) ? x : log1pf(__expf(x)); }
__device__ __forceinline__ ushort f2b(float f) {
  uint u = __float_as_uint(f);
  u += 0x7fff + ((u >> 16) & 1);
  return (ushort)(u >> 16);
}
__device__ __forceinline__ float b2f(ushort h) { return __uint_as_float(((uint)h) << 16); }

// ---------------- out = x ----------------
__global__ void k_copy_out(const float* __restrict__ x, float* __restrict__ o, int n) {
  int i = blockIdx.x * 256 + threadIdx.x;
  if (i < n) o[i] = x[i];
}

// ---------------- weight prep: fold norm into in_proj, transpose to [N][K] bf16 ----------------
__global__ void k_foldWin(const float* __restrict__ Wi, const float* __restrict__ nw,
                          ushort* __restrict__ Wct) {
  int i = blockIdx.x * 256 + threadIdx.x;      // i = n*192 + k, n<768, k<192
  if (i >= 768 * DM) return;
  int n = i / DM, k = i % DM;
  Wct[i] = f2b(nw[k] * Wi[(size_t)k * 768 + n]);
}

// transpose W[K][N] (ld N) -> Wt[NP][K] bf16, zero-pad rows n>=N
__global__ void k_tr(const float* __restrict__ W, ushort* __restrict__ Wt,
                     int N, int K, int NP) {
  int i = blockIdx.x * 256 + threadIdx.x;
  if (i >= NP * K) return;
  int n = i / K, k = i % K;
  Wt[i] = (n < N) ? f2b(W[(size_t)k * N + n]) : (ushort)0;
}

// ---------------- gather + rmsnorm -> bf16 ----------------
__global__ __launch_bounds__(64) void k_gather_rms(const float* __restrict__ x,
                                                   const int* __restrict__ idx,
                                                   ushort* __restrict__ xon) {
  int t = blockIdx.x;
  int lane = threadIdx.x;
  int r = idx[t];
  float v0 = x[(size_t)r*DM + lane];
  float v1 = x[(size_t)r*DM + 64 + lane];
  float v2 = x[(size_t)r*DM + 128 + lane];
  float ss = v0*v0 + v1*v1 + v2*v2;
  #pragma unroll
  for (int o = 32; o > 0; o >>= 1) ss += __shfl_xor(ss, o);
  float s = rsqrtf(ss * (1.f/DM) + EPSV);
  xon[(size_t)t*DM + lane]       = f2b(v0 * s);
  xon[(size_t)t*DM + 64 + lane]  = f2b(v1 * s);
  xon[(size_t)t*DM + 128 + lane] = f2b(v2 * s);
}

// ---------------- MFMA GEMM: C(MxN) = A(MxK) @ Bt(N,K)^T ----------------
// 128x64 tile, 4 waves (2M x 2N), mfma_f32_16x16x32_bf16, XOR-swizzled LDS.
// AMODE 0: A bf16 (lda). AMODE 1: A[m][k] = Y[m*lda+k] * silu(Z[m*ldz+k]).
// OMODE 0: f32 out. OMODE 1: bf16 out. K % 64 == 0.
template<int AMODE, int OMODE>
__global__ __launch_bounds__(256) void k_mm(
    const ushort* __restrict__ A, const float* __restrict__ Yp,
    const ushort* __restrict__ Zp, const ushort* __restrict__ Bt,
    void* __restrict__ Cp, int N, int K, int lda, int ldz, int ldc)
{
  __shared__ __align__(16) ushort As[128 * 64];
  __shared__ __align__(16) ushort Bs[64 * 64];
  const int bm = blockIdx.y * 128, bn = blockIdx.x * 64;
  const int tid = threadIdx.x;
  const int l = tid & 63, w = tid >> 6;
  const int wm = w & 1, wn = w >> 1;
  f32x4 acc[4][2] = {};

  for (int k0 = 0; k0 < K; k0 += 64) {
    // stage A tile 128x64 bf16 (16B chunks, XOR swizzle)
    #pragma unroll
    for (int p = 0; p < 4; p++) {
      int c = tid + p * 256;
      int row = c >> 3, ko = (c & 7) * 8;
      int sw = (row * 128 + (c & 7) * 16) ^ ((row & 7) << 4);
      if (AMODE == 0) {
        uint4 v = *(const uint4*)(A + (size_t)(bm + row) * lda + k0 + ko);
        *(uint4*)((char*)As + sw) = v;
      } else {
        const float*  yrow = Yp + (size_t)(bm + row) * lda + k0 + ko;
        const ushort* zrow = Zp + (size_t)(bm + row) * ldz + k0 + ko;
        ushort tmp[8];
        #pragma unroll
        for (int j = 0; j < 8; j++) {
          float z = b2f(zrow[j]);
          tmp[j] = f2b(yrow[j] * (z / (1.f + __expf(-z))));
        }
        *(uint4*)((char*)As + sw) = *(const uint4*)tmp;
      }
    }
    // stage B tile 64x64 bf16
    #pragma unroll
    for (int p = 0; p < 2; p++) {
      int c = tid + p * 256;
      int row = c >> 3, ko = (c & 7) * 8;
      int sw = (row * 128 + (c & 7) * 16) ^ ((row & 7) << 4);
      uint4 v = *(const uint4*)(Bt + (size_t)(bn + row) * K + k0 + ko);
      *(uint4*)((char*)Bs + sw) = v;
    }
    __syncthreads();
    #pragma unroll
    for (int ks = 0; ks < 2; ks++) {
      bf16x8 af[4], bfv[2];
      #pragma unroll
      for (int mi = 0; mi < 4; mi++) {
        int r = 64 * wm + 16 * mi + (l & 15);
        int ad = (r * 128 + 32 * ks + 16 * (l >> 4)) ^ ((r & 7) << 4);
        af[mi] = *(const bf16x8*)((const char*)As + ad);
      }
      #pragma unroll
      for (int ni = 0; ni < 2; ni++) {
        int r = 32 * wn + 16 * ni + (l & 15);
        int ad = (r * 128 + 32 * ks + 16 * (l >> 4)) ^ ((r & 7) << 4);
        bfv[ni] = *(const bf16x8*)((const char*)Bs + ad);
      }
      #pragma unroll
      for (int mi = 0; mi < 4; mi++)
        #pragma unroll
        for (int ni = 0; ni < 2; ni++)
          acc[mi][ni] = __builtin_amdgcn_mfma_f32_16x16x32_bf16(
              af[mi], bfv[ni], acc[mi][ni], 0, 0, 0);
    }
    __syncthreads();
  }

  // epilogue: D[row=4*(l>>4)+j][col=l&15]
  #pragma unroll
  for (int mi = 0; mi < 4; mi++) {
    #pragma unroll
    for (int ni = 0; ni < 2; ni++) {
      int c0 = bn + 32 * wn + 16 * ni + (l & 15);
      if (c0 < N) {
        int r0 = bm + 64 * wm + 16 * mi + 4 * (l >> 4);
        #pragma unroll
        for (int j = 0; j < 4; j++) {
          if (OMODE == 0)
            ((float*)Cp)[(size_t)(r0 + j) * ldc + c0] = acc[mi][ni][j];
          else
            ((ushort*)Cp)[(size_t)(r0 + j) * ldc + c0] = f2b(acc[mi][ni][j]);
        }
      }
    }
  }
}

// ---------------- causal depthwise conv + silu (bf16 in/out) ----------------
__global__ void k_conv(const ushort* __restrict__ XZ, int sgn,
                       const float* __restrict__ cw, const float* __restrict__ cb,
                       ushort* __restrict__ U) {
  int i = blockIdx.x * 256 + threadIdx.x;
  if (i >= LSEQ * DI) return;
  int t = i / DI, d = i % DI;
  float acc = cb[d];
  #pragma unroll
  for (int k = 0; k < DCONV; k++) {
    int r = (sgn > 0) ? (t - (DCONV-1) + k) : (t + (DCONV-1) - k);
    if (r >= 0 && r < LSEQ) acc += cw[d*DCONV + k] * b2f(XZ[(size_t)r*768 + d]);
  }
  U[i] = f2b(siluf(acc));
}

// ---------------- dt = softplus(proj[:, :12] @ Wdt + bdt) ----------------
__global__ __launch_bounds__(384) void k_dt(const float* __restrict__ P,
                                            const float* __restrict__ Wdt,
                                            const float* __restrict__ bdt,
                                            float* __restrict__ DT) {
  __shared__ float pr[DTRK];
  int t = blockIdx.x, d = threadIdx.x;
  if (d < DTRK) pr[d] = P[(size_t)t*NPROJ + d];
  __syncthreads();
  float acc = bdt[d];
  #pragma unroll
  for (int k = 0; k < DTRK; k++) acc += pr[k] * Wdt[k*DI + d];
  DT[(size_t)t*DI + d] = softplusf(acc);
}

// ---------------- scan phase 1 ----------------
__global__ __launch_bounds__(128) void k_scan1(const float* __restrict__ DT,
                                               const ushort* __restrict__ U,
                                               const float* __restrict__ PROJ,
                                               const float* __restrict__ Alog,
                                               int sgn,
                                               float* __restrict__ Pc,
                                               float* __restrict__ Sc) {
  __shared__ float Bsm[TCH][DSN];
  int c = blockIdx.y;
  int d = blockIdx.x * 128 + threadIdx.x;
  for (int i = threadIdx.x; i < TCH*DSN; i += 128) {
    int t = i >> 4, n = i & 15;
    int tt = c*TCH + t;
    int row = (sgn > 0) ? tt : (LSEQ-1-tt);
    Bsm[t][n] = PROJ[(size_t)row*NPROJ + DTRK + n];
  }
  __syncthreads();
  float A[DSN], S[DSN];
  #pragma unroll
  for (int n = 0; n < DSN; n++) { A[n] = -__expf(Alog[d*DSN + n]); S[n] = 0.f; }
  float dtsum = 0.f;
  for (int t = 0; t < TCH; t++) {
    int tt = c*TCH + t;
    int row = (sgn > 0) ? tt : (LSEQ-1-tt);
    float dtv = DT[(size_t)row*DI + d];
    float du  = dtv * b2f(U[(size_t)row*DI + d]);
    dtsum += dtv;
    #pragma unroll
    for (int n = 0; n < DSN; n++) {
      float a = __expf(dtv * A[n]);
      S[n] = a * S[n] + du * Bsm[t][n];
    }
  }
  size_t base = (size_t)c * (DI*DSN) + (size_t)d * DSN;
  #pragma unroll
  for (int n = 0; n < DSN; n++) {
    Pc[base + n] = __expf(A[n] * dtsum);
    Sc[base + n] = S[n];
  }
}

// ---------------- scan phase 2 ----------------
__global__ void k_scan2(const float* __restrict__ Pc, const float* __restrict__ Sc,
                        float* __restrict__ Hc) {
  int g = blockIdx.x * blockDim.x + threadIdx.x;  // 6144 = DI*DSN
  float H = 0.f;
  for (int c = 0; c < NCH; c++) {
    size_t o = (size_t)c * (DI*DSN) + g;
    Hc[o] = H;
    H = Pc[o] * H + Sc[o];
  }
}

// ---------------- scan phase 3: emit y (f32) into ybuf ----------------
__global__ __launch_bounds__(128) void k_scan3(const float* __restrict__ DT,
                                               const ushort* __restrict__ U,
                                               const float* __restrict__ PROJ,
                                               const float* __restrict__ Alog,
                                               const float* __restrict__ Dp,
                                               const float* __restrict__ Hc,
                                               int sgn,
                                               float* __restrict__ Y /* ld 384 */) {
  __shared__ float Bsm[TCH][DSN];
  __shared__ float Csm[TCH][DSN];
  int c = blockIdx.y;
  int d = blockIdx.x * 128 + threadIdx.x;
  for (int i = threadIdx.x; i < TCH*DSN; i += 128) {
    int t = i >> 4, n = i & 15;
    int tt = c*TCH + t;
    int row = (sgn > 0) ? tt : (LSEQ-1-tt);
    Bsm[t][n] = PROJ[(size_t)row*NPROJ + DTRK + n];
    Csm[t][n] = PROJ[(size_t)row*NPROJ + DTRK + DSN + n];
  }
  __syncthreads();
  float A[DSN], h[DSN];
  size_t hb = (size_t)c*(DI*DSN) + (size_t)d*DSN;
  #pragma unroll
  for (int n = 0; n < DSN; n++) { A[n] = -__expf(Alog[d*DSN+n]); h[n] = Hc[hb+n]; }
  float dskip = Dp[d];
  for (int t = 0; t < TCH; t++) {
    int tt = c*TCH + t;
    int row = (sgn > 0) ? tt : (LSEQ-1-tt);
    float dtv = DT[(size_t)row*DI + d];
    float uv  = b2f(U[(size_t)row*DI + d]);
    float du = dtv * uv;
    float y = uv * dskip;
    #pragma unroll
    for (int n = 0; n < DSN; n++) {
      float a = __expf(dtv * A[n]);
      h[n] = a * h[n] + du * Bsm[t][n];
      y += h[n] * Csm[t][n];
    }
    Y[(size_t)row * DI + d] = y;
  }
}

// ---------------- final combine ----------------
__device__ __forceinline__ void ln_row(float (&v)[3], const float* __restrict__ w,
                                       const float* __restrict__ b, int lane) {
  float s = v[0] + v[1] + v[2];
  #pragma unroll
  for (int o = 32; o > 0; o >>= 1) s += __shfl_xor(s, o);
  float m = s * (1.f / DM);
  float q = 0.f;
  #pragma unroll
  for (int i = 0; i < 3; i++) { float d = v[i] - m; q += d*d; }
  #pragma unroll
  for (int o = 32; o > 0; o >>= 1) q += __shfl_xor(q, o);
  float inv = rsqrtf(q * (1.f / DM) + EPSV);
  #pragma unroll
  for (int i = 0; i < 3; i++) v[i] = (v[i] - m) * inv * w[lane + 64*i] + b[lane + 64*i];
}

__global__ __launch_bounds__(64) void k_final(const float* __restrict__ x,
                                              const int* __restrict__ idx,
                                              const float* __restrict__ G4f,
                                              const float* __restrict__ G4b,
                                              const float* __restrict__ lnfw,
                                              const float* __restrict__ lnfb,
                                              const float* __restrict__ lnbw,
                                              const float* __restrict__ lnbb,
                                              const float* __restrict__ lnow,
                                              const float* __restrict__ lnob,
                                              float* __restrict__ out) {
  int t = blockIdx.x, lane = threadIdx.x;
  int r = idx[t];
  float f[3], g[3], cb[3];
  #pragma unroll
  for (int i = 0; i < 3; i++) {
    int j = lane + 64*i;
    float xo = x[(size_t)r*DM + j];
    f[i] = xo + G4f[(size_t)t*DM + j];
    g[i] = xo + G4b[(size_t)t*DM + j];
  }
  ln_row(f, lnfw, lnfb, lane);
  ln_row(g, lnbw, lnbb, lane);
  #pragma unroll
  for (int i = 0; i < 3; i++) cb[i] = f[i] + g[i];
  ln_row(cb, lnow, lnob, lane);
  #pragma unroll
  for (int i = 0; i < 3; i++) {
    int j = lane + 64*i;
    out[(size_t)r*DM + j] += cb[i];
  }
}

extern "C" void kernel_launch(void* const* d_in, const int* in_sizes, int n_in,
                              void* d_out, int out_size, void* d_ws, size_t ws_size,
                              hipStream_t stream) {
  const float* x      = (const float*)d_in[0];
  const int*   orders = (const int*)  d_in[1];
  const float* nw     = (const float*)d_in[2];
  const float* Wi     = (const float*)d_in[3];
  const float* cw     = (const float*)d_in[4];
  const float* cbi    = (const float*)d_in[5];
  const float* Wx     = (const float*)d_in[6];
  const float* Wdt    = (const float*)d_in[7];
  const float* bdt    = (const float*)d_in[8];
  const float* Alog   = (const float*)d_in[9];
  const float* Dp     = (const float*)d_in[10];
  const float* Wo     = (const float*)d_in[11];
  const float* flw    = (const float*)d_in[12];
  const float* flb    = (const float*)d_in[13];
  const float* blw    = (const float*)d_in[14];
  const float* blb    = (const float*)d_in[15];
  const float* olw    = (const float*)d_in[16];
  const float* olb    = (const float*)d_in[17];
  float* outp = (float*)d_out;

  char* w = (char*)d_ws;
  size_t off = 0;
  auto take = [&](size_t bytes) -> void* {
    char* p = w + off;
    off += (bytes + 255) & ~(size_t)255;
    return (void*)p;
  };
  ushort* Wct  = (ushort*)take((size_t)768 * DM * 2);      // in-proj weight, [768][192] bf16
  ushort* Wxt  = (ushort*)take((size_t)64 * DI * 2);       // x-proj weight,  [64][384] bf16 (padded)
  ushort* Wot  = (ushort*)take((size_t)DM * DI * 2);       // out-proj weight,[192][384] bf16
  ushort* xon  = (ushort*)take((size_t)LSEQ * DM * 2);     // normed gathered x, bf16
  ushort* xz   = (ushort*)take((size_t)LSEQ * 768 * 2);    // in-proj out, bf16
  ushort* uc   = (ushort*)take((size_t)LSEQ * DI * 2);     // conv out, bf16
  float*  ybuf = (float*) take((size_t)LSEQ * DI * 4);     // scan out, f32
  float*  proj = (float*) take((size_t)LSEQ * NPROJ * 4);
  float*  dtf  = (float*) take((size_t)LSEQ * DI * 4);     // dt, later g4f (L x 192)
  float*  dtb  = (float*) take((size_t)LSEQ * DI * 4);
  float*  Pc   = (float*) take((size_t)NCH * DI * DSN * 4);
  float*  Sc   = (float*) take((size_t)NCH * DI * DSN * 4);
  float*  Hc   = (float*) take((size_t)NCH * DI * DSN * 4);
  (void)ws_size; (void)n_in; (void)in_sizes; (void)out_size;

  k_copy_out<<<(LSEQ*DM + 255)/256, 256, 0, stream>>>(x, outp, LSEQ*DM);

  for (int o = 0; o < 2; o++) {
    const int* idx = orders + (size_t)o * LSEQ;
    k_gather_rms<<<LSEQ, 64, 0, stream>>>(x, idx, xon);

    for (int dir = 0; dir < 2; dir++) {
      int blk = (dir == 0) ? o : 2 + o;
      int sgn = (dir == 0) ? 1 : -1;
      float* dtbuf = (dir == 0) ? dtf : dtb;    // dt during scan, g4 after

      // weight prep
      k_foldWin<<<(768*DM + 255)/256, 256, 0, stream>>>(
          Wi + (size_t)blk*DM*768, nw + (size_t)blk*DM, Wct);
      k_tr<<<(64*DI + 255)/256, 256, 0, stream>>>(
          Wx + (size_t)blk*DI*NPROJ, Wxt, NPROJ, DI, 64);
      k_tr<<<(DM*DI + 255)/256, 256, 0, stream>>>(
          Wo + (size_t)blk*DI*DM, Wot, DM, DI, DM);

      // in-proj: xz(bf16, ld 768) = xon @ Wc
      k_mm<0,1><<<dim3(768/64, LSEQ/128), 256, 0, stream>>>(
          xon, nullptr, nullptr, Wct, xz, 768, DM, DM, 0, 768);
      // conv
      k_conv<<<(LSEQ*DI + 255)/256, 256, 0, stream>>>(
          xz, sgn, cw + (size_t)blk*DI*DCONV, cbi + (size_t)blk*DI, uc);
      // x-proj: proj(f32, ld 44) = uc @ Wx
      k_mm<0,0><<<dim3(1, LSEQ/128), 256, 0, stream>>>(
          uc, nullptr, nullptr, Wxt, proj, NPROJ, DI, DI, 0, NPROJ);
      k_dt<<<LSEQ, DI, 0, stream>>>(
          proj, Wdt + (size_t)blk*DTRK*DI, bdt + (size_t)blk*DI, dtbuf);
      k_scan1<<<dim3(DI/128, NCH), 128, 0, stream>>>(
          dtbuf, uc, proj, Alog + (size_t)blk*DI*DSN, sgn, Pc, Sc);
      k_scan2<<<(DI*DSN)/256, 256, 0, stream>>>(Pc, Sc, Hc);
      k_scan3<<<dim3(DI/128, NCH), 128, 0, stream>>>(
          dtbuf, uc, proj, Alog + (size_t)blk*DI*DSN, Dp + (size_t)blk*DI, Hc, sgn, ybuf);
      // out-proj: g4(f32, ld 192) = (y * silu(z)) @ Wo ; overwrite dt buffer
      k_mm<1,0><<<dim3(DM/64, LSEQ/128), 256, 0, stream>>>(
          nullptr, ybuf, xz + 384, Wot, dtbuf, DM, DI, DI, 768, DM);
    }
    k_final<<<LSEQ, 64, 0, stream>>>(x, idx, dtf, dtb,
        flw + (size_t)o*DM, flb + (size_t)o*DM,
        blw + (size_t)o*DM, blb + (size_t)o*DM,
        olw + (size_t)o*DM, olb + (size_t)o*DM, outp);
  }
}

// Round 3
// 792.725 us; speedup vs baseline: 1.9677x; 1.4299x over previous
//
#include <hip/hip_runtime.h>
#include <math.h>

#define LSEQ 16384
#define DM 192
#define DI 384
#define DSN 16
#define DCONV 4
#define DTRK 12
#define NPROJ 44   /* DTRK + 2*DSN */
#define EPSV 1e-5f
#define TCH 32
#define NCH (LSEQ / TCH)

typedef __attribute__((ext_vector_type(8))) short bf16x8;
typedef __attribute__((ext_vector_type(4))) float f32x4;

__device__ __forceinline__ float siluf(float x) { return x / (1.f + __expf(-x)); }
__device__ __forceinline__ float softplus_f(float x) {
  float e = __expf(x);
  float l = __logf(1.f + e);
  return (x > 20.f) ? x : l;
}
__device__ __forceinline__ ushort f2b(float f) {
  uint u = __float_as_uint(f);
  u += 0x7fff + ((u >> 16) & 1);
  return (ushort)(u >> 16);
}
__device__ __forceinline__ float b2f(ushort h) { return __uint_as_float(((uint)h) << 16); }

// a[n] = q^(n+1), log-depth
__device__ __forceinline__ void pow16(float q, float (&a)[16]) {
  float q2 = q*q, q4 = q2*q2, q8 = q4*q4;
  a[0]=q;        a[1]=q2;       a[2]=q2*q;      a[3]=q4;
  a[4]=q4*q;     a[5]=q4*q2;    a[6]=q4*q2*q;   a[7]=q8;
  a[8]=q8*q;     a[9]=q8*q2;    a[10]=q8*q2*q;  a[11]=q8*q4;
  a[12]=q8*q4*q; a[13]=q8*q4*q2;a[14]=q8*q4*q2*q;a[15]=q8*q8;
}

// ---------------- out = x (float4) ----------------
__global__ void k_copy_out(const float4* __restrict__ x, float4* __restrict__ o, int n4) {
  int i = blockIdx.x * 256 + threadIdx.x;
  if (i < n4) o[i] = x[i];
}

// ---------------- weight prep (all 4 blocks at once) ----------------
// in_proj: fold norm, transpose to [768][192] bf16
__global__ void k_foldWin(const float* __restrict__ Wi, const float* __restrict__ nw,
                          ushort* __restrict__ Wct) {
  int i = blockIdx.x * 256 + threadIdx.x;      // over 4*768*192
  if (i >= 4 * 768 * DM) return;
  int blk = i / (768 * DM), j = i % (768 * DM);
  int n = j / DM, k = j % DM;
  Wct[i] = f2b(nw[blk*DM + k] * Wi[(size_t)blk*DM*768 + (size_t)k*768 + n]);
}

// transpose W[K][N] -> Wt[NP][K] bf16, zero-pad n>=N, for 4 blocks
__global__ void k_tr4(const float* __restrict__ W, ushort* __restrict__ Wt,
                      int N, int K, int NP) {
  int i = blockIdx.x * 256 + threadIdx.x;
  if (i >= 4 * NP * K) return;
  int blk = i / (NP * K), j = i % (NP * K);
  int n = j / K, k = j % K;
  Wt[i] = (n < N) ? f2b(W[(size_t)blk*K*N + (size_t)k*N + n]) : (ushort)0;
}

// ---------------- gather + rmsnorm -> bf16 ----------------
__global__ __launch_bounds__(64) void k_gather_rms(const float* __restrict__ x,
                                                   const int* __restrict__ idx,
                                                   ushort* __restrict__ xon) {
  int t = blockIdx.x;
  int lane = threadIdx.x;
  int r = idx[t];
  float v0 = x[(size_t)r*DM + lane];
  float v1 = x[(size_t)r*DM + 64 + lane];
  float v2 = x[(size_t)r*DM + 128 + lane];
  float ss = v0*v0 + v1*v1 + v2*v2;
  #pragma unroll
  for (int o = 32; o > 0; o >>= 1) ss += __shfl_xor(ss, o);
  float s = rsqrtf(ss * (1.f/DM) + EPSV);
  xon[(size_t)t*DM + lane]       = f2b(v0 * s);
  xon[(size_t)t*DM + 64 + lane]  = f2b(v1 * s);
  xon[(size_t)t*DM + 128 + lane] = f2b(v2 * s);
}

// ---------------- MFMA GEMM: C(MxN) = A(MxK) @ Bt(N,K)^T ----------------
// BM = 32*MI rows, 64 cols, 4 waves (2M x 2N), mfma_f32_16x16x32_bf16.
// AMODE 0: A bf16. AMODE 1: A[m][k] = Y[m*lda+k] * silu(Z[m*ldz+k]).
// OMODE 0: f32 out. OMODE 1: bf16 out. K % 64 == 0, M % BM == 0.
template<int MI, int AMODE, int OMODE>
__global__ __launch_bounds__(256) void k_mm(
    const ushort* __restrict__ A, const float* __restrict__ Yp,
    const ushort* __restrict__ Zp, const ushort* __restrict__ Bt,
    void* __restrict__ Cp, int N, int K, int lda, int ldz, int ldc)
{
  __shared__ __align__(16) ushort As[32 * MI * 64];
  __shared__ __align__(16) ushort Bs[64 * 64];
  const int bm = blockIdx.y * (32 * MI), bn = blockIdx.x * 64;
  const int tid = threadIdx.x;
  const int l = tid & 63, w = tid >> 6;
  const int wm = w & 1, wn = w >> 1;
  f32x4 acc[MI][2] = {};

  for (int k0 = 0; k0 < K; k0 += 64) {
    #pragma unroll
    for (int p = 0; p < MI; p++) {
      int c = tid + p * 256;
      int row = c >> 3, ko = (c & 7) * 8;
      int sw = (row * 128 + (c & 7) * 16) ^ ((row & 7) << 4);
      if (AMODE == 0) {
        uint4 v = *(const uint4*)(A + (size_t)(bm + row) * lda + k0 + ko);
        *(uint4*)((char*)As + sw) = v;
      } else {
        const float*  yrow = Yp + (size_t)(bm + row) * lda + k0 + ko;
        const ushort* zrow = Zp + (size_t)(bm + row) * ldz + k0 + ko;
        ushort tmp[8];
        #pragma unroll
        for (int j = 0; j < 8; j++) {
          float z = b2f(zrow[j]);
          tmp[j] = f2b(yrow[j] * (z / (1.f + __expf(-z))));
        }
        *(uint4*)((char*)As + sw) = *(const uint4*)tmp;
      }
    }
    #pragma unroll
    for (int p = 0; p < 2; p++) {
      int c = tid + p * 256;
      int row = c >> 3, ko = (c & 7) * 8;
      int sw = (row * 128 + (c & 7) * 16) ^ ((row & 7) << 4);
      uint4 v = *(const uint4*)(Bt + (size_t)(bn + row) * K + k0 + ko);
      *(uint4*)((char*)Bs + sw) = v;
    }
    __syncthreads();
    #pragma unroll
    for (int ks = 0; ks < 2; ks++) {
      bf16x8 af[MI], bfv[2];
      #pragma unroll
      for (int mi = 0; mi < MI; mi++) {
        int r = 16 * MI * wm + 16 * mi + (l & 15);
        int ad = (r * 128 + 32 * ks + 16 * (l >> 4)) ^ ((r & 7) << 4);
        af[mi] = *(const bf16x8*)((const char*)As + ad);
      }
      #pragma unroll
      for (int ni = 0; ni < 2; ni++) {
        int r = 32 * wn + 16 * ni + (l & 15);
        int ad = (r * 128 + 32 * ks + 16 * (l >> 4)) ^ ((r & 7) << 4);
        bfv[ni] = *(const bf16x8*)((const char*)Bs + ad);
      }
      #pragma unroll
      for (int mi = 0; mi < MI; mi++)
        #pragma unroll
        for (int ni = 0; ni < 2; ni++)
          acc[mi][ni] = __builtin_amdgcn_mfma_f32_16x16x32_bf16(
              af[mi], bfv[ni], acc[mi][ni], 0, 0, 0);
    }
    __syncthreads();
  }

  #pragma unroll
  for (int mi = 0; mi < MI; mi++) {
    #pragma unroll
    for (int ni = 0; ni < 2; ni++) {
      int c0 = bn + 32 * wn + 16 * ni + (l & 15);
      if (c0 < N) {
        int r0 = bm + 16 * MI * wm + 16 * mi + 4 * (l >> 4);
        #pragma unroll
        for (int j = 0; j < 4; j++) {
          if (OMODE == 0)
            ((float*)Cp)[(size_t)(r0 + j) * ldc + c0] = acc[mi][ni][j];
          else
            ((ushort*)Cp)[(size_t)(r0 + j) * ldc + c0] = f2b(acc[mi][ni][j]);
        }
      }
    }
  }
}

// ---------------- causal depthwise conv + silu (bf16 in/out) ----------------
__global__ void k_conv(const ushort* __restrict__ XZ, int sgn,
                       const float* __restrict__ cw, const float* __restrict__ cb,
                       ushort* __restrict__ U) {
  int i = blockIdx.x * 256 + threadIdx.x;
  if (i >= LSEQ * DI) return;
  int t = i / DI, d = i % DI;
  float acc = cb[d];
  #pragma unroll
  for (int k = 0; k < DCONV; k++) {
    int r = (sgn > 0) ? (t - (DCONV-1) + k) : (t + (DCONV-1) - k);
    if (r >= 0 && r < LSEQ) acc += cw[d*DCONV + k] * b2f(XZ[(size_t)r*768 + d]);
  }
  U[i] = f2b(siluf(acc));
}

// ---------------- scan phase 1: fused dt, chunk-local scan + chunk product ----------------
__global__ __launch_bounds__(128) void k_scan1(const ushort* __restrict__ U,
                                               const float* __restrict__ PROJ,
                                               const float* __restrict__ Alog,
                                               const float* __restrict__ Wdt,
                                               const float* __restrict__ bdt,
                                               int sgn,
                                               float* __restrict__ Pc,
                                               float* __restrict__ Sc) {
  __shared__ float Ps[TCH][NPROJ];
  int c = blockIdx.y;
  int d = blockIdx.x * 128 + threadIdx.x;
  for (int j = threadIdx.x; j < TCH * 11; j += 128) {
    int row = j / 11, q4 = j % 11;
    int s = c*TCH + row;
    int rg = (sgn > 0) ? s : (LSEQ-1-s);
    *(float4*)&Ps[row][q4*4] = *(const float4*)(PROJ + (size_t)rg*NPROJ + q4*4);
  }
  __syncthreads();

  float wdt[DTRK];
  #pragma unroll
  for (int k = 0; k < DTRK; k++) wdt[k] = Wdt[k*DI + d];
  float bdtv = bdt[d];
  float A[DSN]; bool fast = true;
  #pragma unroll
  for (int n = 0; n < DSN; n++) {
    A[n] = -__expf(Alog[d*DSN + n]);
    fast = fast && (fabsf(A[n] + (float)(n+1)) <= 1e-3f * (n+1));
  }
  float S[DSN] = {};
  float dtsum = 0.f;
  for (int t = 0; t < TCH; t++) {
    int s = c*TCH + t;
    int row = (sgn > 0) ? s : (LSEQ-1-s);
    float u = b2f(U[(size_t)row*DI + d]);
    float xdt = bdtv;
    #pragma unroll
    for (int k = 0; k < DTRK; k++) xdt += Ps[t][k] * wdt[k];
    float dtv = softplus_f(xdt);
    float du = dtv * u;
    dtsum += dtv;
    float a[DSN];
    if (fast) { pow16(__expf(-dtv), a); }
    else {
      #pragma unroll
      for (int n = 0; n < DSN; n++) a[n] = __expf(dtv * A[n]);
    }
    #pragma unroll
    for (int n = 0; n < DSN; n++)
      S[n] = a[n] * S[n] + du * Ps[t][DTRK + n];
  }
  float P[DSN];
  if (fast) { pow16(__expf(-dtsum), P); }
  else {
    #pragma unroll
    for (int n = 0; n < DSN; n++) P[n] = __expf(A[n] * dtsum);
  }
  size_t base = (size_t)c * (DI*DSN) + (size_t)d * DSN;
  #pragma unroll
  for (int n = 0; n < DSN; n++) { Pc[base + n] = P[n]; Sc[base + n] = S[n]; }
}

// ---------------- scan phase 2: exclusive prefix over chunk summaries ----------------
__global__ void k_scan2(const float* __restrict__ Pc, const float* __restrict__ Sc,
                        float* __restrict__ Hc) {
  int g = blockIdx.x * blockDim.x + threadIdx.x;  // 6144 = DI*DSN
  float H = 0.f;
  #pragma unroll 8
  for (int c = 0; c < NCH; c++) {
    size_t o = (size_t)c * (DI*DSN) + g;
    Hc[o] = H;
    H = fmaf(Pc[o], H, Sc[o]);
  }
}

// ---------------- scan phase 3: fused dt, rescan with init state, emit y ----------------
__global__ __launch_bounds__(128) void k_scan3(const ushort* __restrict__ U,
                                               const float* __restrict__ PROJ,
                                               const float* __restrict__ Alog,
                                               const float* __restrict__ Wdt,
                                               const float* __restrict__ bdt,
                                               const float* __restrict__ Dp,
                                               const float* __restrict__ Hc,
                                               int sgn,
                                               float* __restrict__ Y /* ld 384 */) {
  __shared__ float Ps[TCH][NPROJ];
  int c = blockIdx.y;
  int d = blockIdx.x * 128 + threadIdx.x;
  for (int j = threadIdx.x; j < TCH * 11; j += 128) {
    int row = j / 11, q4 = j % 11;
    int s = c*TCH + row;
    int rg = (sgn > 0) ? s : (LSEQ-1-s);
    *(float4*)&Ps[row][q4*4] = *(const float4*)(PROJ + (size_t)rg*NPROJ + q4*4);
  }
  __syncthreads();

  float wdt[DTRK];
  #pragma unroll
  for (int k = 0; k < DTRK; k++) wdt[k] = Wdt[k*DI + d];
  float bdtv = bdt[d];
  float A[DSN]; bool fast = true;
  #pragma unroll
  for (int n = 0; n < DSN; n++) {
    A[n] = -__expf(Alog[d*DSN + n]);
    fast = fast && (fabsf(A[n] + (float)(n+1)) <= 1e-3f * (n+1));
  }
  float h[DSN];
  size_t hb = (size_t)c*(DI*DSN) + (size_t)d*DSN;
  #pragma unroll
  for (int n = 0; n < DSN; n++) h[n] = Hc[hb + n];
  float dskip = Dp[d];

  for (int t = 0; t < TCH; t++) {
    int s = c*TCH + t;
    int row = (sgn > 0) ? s : (LSEQ-1-s);
    float u = b2f(U[(size_t)row*DI + d]);
    float xdt = bdtv;
    #pragma unroll
    for (int k = 0; k < DTRK; k++) xdt += Ps[t][k] * wdt[k];
    float dtv = softplus_f(xdt);
    float du = dtv * u;
    float a[DSN];
    if (fast) { pow16(__expf(-dtv), a); }
    else {
      #pragma unroll
      for (int n = 0; n < DSN; n++) a[n] = __expf(dtv * A[n]);
    }
    float y = u * dskip;
    #pragma unroll
    for (int n = 0; n < DSN; n++) {
      h[n] = a[n] * h[n] + du * Ps[t][DTRK + n];
      y += h[n] * Ps[t][DTRK + DSN + n];
    }
    Y[(size_t)row * DI + d] = y;
  }
}

// ---------------- final combine ----------------
__device__ __forceinline__ void ln_row(float (&v)[3], const float* __restrict__ w,
                                       const float* __restrict__ b, int lane) {
  float s = v[0] + v[1] + v[2];
  #pragma unroll
  for (int o = 32; o > 0; o >>= 1) s += __shfl_xor(s, o);
  float m = s * (1.f / DM);
  float q = 0.f;
  #pragma unroll
  for (int i = 0; i < 3; i++) { float d = v[i] - m; q += d*d; }
  #pragma unroll
  for (int o = 32; o > 0; o >>= 1) q += __shfl_xor(q, o);
  float inv = rsqrtf(q * (1.f / DM) + EPSV);
  #pragma unroll
  for (int i = 0; i < 3; i++) v[i] = (v[i] - m) * inv * w[lane + 64*i] + b[lane + 64*i];
}

__global__ __launch_bounds__(64) void k_final(const float* __restrict__ x,
                                              const int* __restrict__ idx,
                                              const float* __restrict__ G4f,
                                              const float* __restrict__ G4b,
                                              const float* __restrict__ lnfw,
                                              const float* __restrict__ lnfb,
                                              const float* __restrict__ lnbw,
                                              const float* __restrict__ lnbb,
                                              const float* __restrict__ lnow,
                                              const float* __restrict__ lnob,
                                              float* __restrict__ out) {
  int t = blockIdx.x, lane = threadIdx.x;
  int r = idx[t];
  float f[3], g[3], cb[3];
  #pragma unroll
  for (int i = 0; i < 3; i++) {
    int j = lane + 64*i;
    float xo = x[(size_t)r*DM + j];
    f[i] = xo + G4f[(size_t)t*DM + j];
    g[i] = xo + G4b[(size_t)t*DM + j];
  }
  ln_row(f, lnfw, lnfb, lane);
  ln_row(g, lnbw, lnbb, lane);
  #pragma unroll
  for (int i = 0; i < 3; i++) cb[i] = f[i] + g[i];
  ln_row(cb, lnow, lnob, lane);
  #pragma unroll
  for (int i = 0; i < 3; i++) {
    int j = lane + 64*i;
    out[(size_t)r*DM + j] += cb[i];
  }
}

extern "C" void kernel_launch(void* const* d_in, const int* in_sizes, int n_in,
                              void* d_out, int out_size, void* d_ws, size_t ws_size,
                              hipStream_t stream) {
  const float* x      = (const float*)d_in[0];
  const int*   orders = (const int*)  d_in[1];
  const float* nw     = (const float*)d_in[2];
  const float* Wi     = (const float*)d_in[3];
  const float* cw     = (const float*)d_in[4];
  const float* cbi    = (const float*)d_in[5];
  const float* Wx     = (const float*)d_in[6];
  const float* Wdt    = (const float*)d_in[7];
  const float* bdt    = (const float*)d_in[8];
  const float* Alog   = (const float*)d_in[9];
  const float* Dp     = (const float*)d_in[10];
  const float* Wo     = (const float*)d_in[11];
  const float* flw    = (const float*)d_in[12];
  const float* flb    = (const float*)d_in[13];
  const float* blw    = (const float*)d_in[14];
  const float* blb    = (const float*)d_in[15];
  const float* olw    = (const float*)d_in[16];
  const float* olb    = (const float*)d_in[17];
  float* outp = (float*)d_out;

  char* w = (char*)d_ws;
  size_t off = 0;
  auto take = [&](size_t bytes) -> void* {
    char* p = w + off;
    off += (bytes + 255) & ~(size_t)255;
    return (void*)p;
  };
  ushort* Wct  = (ushort*)take((size_t)4 * 768 * DM * 2);
  ushort* Wxt  = (ushort*)take((size_t)4 * 64 * DI * 2);
  ushort* Wot  = (ushort*)take((size_t)4 * DM * DI * 2);
  ushort* xon  = (ushort*)take((size_t)LSEQ * DM * 2);
  ushort* xz   = (ushort*)take((size_t)LSEQ * 768 * 2);
  ushort* uc   = (ushort*)take((size_t)LSEQ * DI * 2);
  float*  ybuf = (float*) take((size_t)LSEQ * DI * 4);
  float*  proj = (float*) take((size_t)LSEQ * NPROJ * 4);
  float*  g4f  = (float*) take((size_t)LSEQ * DM * 4);
  float*  g4b  = (float*) take((size_t)LSEQ * DM * 4);
  float*  Pc   = (float*) take((size_t)NCH * DI * DSN * 4);
  float*  Sc   = (float*) take((size_t)NCH * DI * DSN * 4);
  float*  Hc   = (float*) take((size_t)NCH * DI * DSN * 4);
  (void)ws_size; (void)n_in; (void)in_sizes; (void)out_size;

  k_copy_out<<<(LSEQ*DM/4 + 255)/256, 256, 0, stream>>>(
      (const float4*)x, (float4*)outp, LSEQ*DM/4);

  // weight prep, all 4 blocks, once
  k_foldWin<<<(4*768*DM + 255)/256, 256, 0, stream>>>(Wi, nw, Wct);
  k_tr4<<<(4*64*DI + 255)/256, 256, 0, stream>>>(Wx, Wxt, NPROJ, DI, 64);
  k_tr4<<<(4*DM*DI + 255)/256, 256, 0, stream>>>(Wo, Wot, DM, DI, DM);

  for (int o = 0; o < 2; o++) {
    const int* idx = orders + (size_t)o * LSEQ;
    k_gather_rms<<<LSEQ, 64, 0, stream>>>(x, idx, xon);

    for (int dir = 0; dir < 2; dir++) {
      int blk = (dir == 0) ? o : 2 + o;
      int sgn = (dir == 0) ? 1 : -1;
      float* g4 = (dir == 0) ? g4f : g4b;

      // in-proj: xz(bf16, ld 768) = xon @ Wc
      k_mm<4,0,1><<<dim3(768/64, LSEQ/128), 256, 0, stream>>>(
          xon, nullptr, nullptr, Wct + (size_t)blk*768*DM, xz, 768, DM, DM, 0, 768);
      // conv
      k_conv<<<(LSEQ*DI + 255)/256, 256, 0, stream>>>(
          xz, sgn, cw + (size_t)blk*DI*DCONV, cbi + (size_t)blk*DI, uc);
      // x-proj: proj(f32, ld 44) = uc @ Wx
      k_mm<2,0,0><<<dim3(1, LSEQ/64), 256, 0, stream>>>(
          uc, nullptr, nullptr, Wxt + (size_t)blk*64*DI, proj, NPROJ, DI, DI, 0, NPROJ);
      // scans (dt fused)
      k_scan1<<<dim3(DI/128, NCH), 128, 0, stream>>>(
          uc, proj, Alog + (size_t)blk*DI*DSN, Wdt + (size_t)blk*DTRK*DI,
          bdt + (size_t)blk*DI, sgn, Pc, Sc);
      k_scan2<<<(DI*DSN)/256, 256, 0, stream>>>(Pc, Sc, Hc);
      k_scan3<<<dim3(DI/128, NCH), 128, 0, stream>>>(
          uc, proj, Alog + (size_t)blk*DI*DSN, Wdt + (size_t)blk*DTRK*DI,
          bdt + (size_t)blk*DI, Dp + (size_t)blk*DI, Hc, sgn, ybuf);
      // out-proj: g4(f32, ld 192) = (y * silu(z)) @ Wo
      k_mm<2,1,0><<<dim3(DM/64, LSEQ/64), 256, 0, stream>>>(
          nullptr, ybuf, xz + 384, Wot + (size_t)blk*DM*DI, g4, DM, DI, DI, 768, DM);
    }
    k_final<<<LSEQ, 64, 0, stream>>>(x, idx, g4f, g4b,
        flw + (size_t)o*DM, flb + (size_t)o*DM,
        blw + (size_t)o*DM, blb + (size_t)o*DM,
        olw + (size_t)o*DM, olb + (size_t)o*DM, outp);
  }
}

// Round 4
// 629.288 us; speedup vs baseline: 2.4788x; 1.2597x over previous
//
#include <hip/hip_runtime.h>
#include <math.h>

#define LSEQ 16384
#define DM 192
#define DI 384
#define DSN 16
#define DCONV 4
#define DTRK 12
#define NPROJ 44   /* DTRK + 2*DSN */
#define EPSV 1e-5f
#define TCH 32
#define NCH (LSEQ / TCH)          /* 512 chunks */
#define GDIM (DI * DSN)           /* 6144 sequences */
#define RGRP 8                    /* chunks per group */
#define NGRP (NCH / RGRP)         /* 64 groups */

typedef __attribute__((ext_vector_type(8))) short bf16x8;
typedef __attribute__((ext_vector_type(4))) float f32x4;

__device__ __forceinline__ float siluf(float x) { return x / (1.f + __expf(-x)); }
__device__ __forceinline__ float softplus_f(float x) {
  float e = __expf(x);
  float l = __logf(1.f + e);
  return (x > 20.f) ? x : l;
}
__device__ __forceinline__ ushort f2b(float f) {
  uint u = __float_as_uint(f);
  u += 0x7fff + ((u >> 16) & 1);
  return (ushort)(u >> 16);
}
__device__ __forceinline__ float b2f(ushort h) { return __uint_as_float(((uint)h) << 16); }

// a[n] = q^(n+1), log-depth
__device__ __forceinline__ void pow16(float q, float (&a)[16]) {
  float q2 = q*q, q4 = q2*q2, q8 = q4*q4;
  a[0]=q;        a[1]=q2;       a[2]=q2*q;      a[3]=q4;
  a[4]=q4*q;     a[5]=q4*q2;    a[6]=q4*q2*q;   a[7]=q8;
  a[8]=q8*q;     a[9]=q8*q2;    a[10]=q8*q2*q;  a[11]=q8*q4;
  a[12]=q8*q4*q; a[13]=q8*q4*q2;a[14]=q8*q4*q2*q;a[15]=q8*q8;
}

// ---------------- unified weight prep (all 4 blocks) ----------------
// seg A: fold norm into in_proj, transpose -> Wct[blk][768][192] bf16
// seg B: Wx -> Wxt[blk][64][384] bf16 (zero-pad rows n>=44)
// seg C: Wo -> Wot[blk][192][384] bf16
#define PREP_A (4 * 768 * DM)
#define PREP_B (4 * 64 * DI)
#define PREP_C (4 * DM * DI)
__global__ void k_prep(const float* __restrict__ Wi, const float* __restrict__ nw,
                       const float* __restrict__ Wx, const float* __restrict__ Wo,
                       ushort* __restrict__ Wct, ushort* __restrict__ Wxt,
                       ushort* __restrict__ Wot) {
  int i = blockIdx.x * 256 + threadIdx.x;
  if (i < PREP_A) {
    int blk = i / (768 * DM), j = i % (768 * DM);
    int n = j / DM, k = j % DM;
    Wct[i] = f2b(nw[blk*DM + k] * Wi[(size_t)blk*DM*768 + (size_t)k*768 + n]);
  } else if (i < PREP_A + PREP_B) {
    int q = i - PREP_A;
    int blk = q / (64 * DI), j = q % (64 * DI);
    int n = j / DI, k = j % DI;
    Wxt[q] = (n < NPROJ) ? f2b(Wx[(size_t)blk*DI*NPROJ + (size_t)k*NPROJ + n]) : (ushort)0;
  } else if (i < PREP_A + PREP_B + PREP_C) {
    int q = i - PREP_A - PREP_B;
    int blk = q / (DM * DI), j = q % (DM * DI);
    int n = j / DI, k = j % DI;
    Wot[q] = f2b(Wo[(size_t)blk*DI*DM + (size_t)k*DM + n]);
  }
}

// ---------------- gather + rmsnorm -> bf16 ----------------
__global__ __launch_bounds__(64) void k_gather_rms(const float* __restrict__ x,
                                                   const int* __restrict__ idx,
                                                   ushort* __restrict__ xon) {
  int t = blockIdx.x;
  int lane = threadIdx.x;
  int r = idx[t];
  float v0 = x[(size_t)r*DM + lane];
  float v1 = x[(size_t)r*DM + 64 + lane];
  float v2 = x[(size_t)r*DM + 128 + lane];
  float ss = v0*v0 + v1*v1 + v2*v2;
  #pragma unroll
  for (int o = 32; o > 0; o >>= 1) ss += __shfl_xor(ss, o);
  float s = rsqrtf(ss * (1.f/DM) + EPSV);
  xon[(size_t)t*DM + lane]       = f2b(v0 * s);
  xon[(size_t)t*DM + 64 + lane]  = f2b(v1 * s);
  xon[(size_t)t*DM + 128 + lane] = f2b(v2 * s);
}

// ---------------- MFMA GEMM: C(MxN) = A(MxK) @ Bt(N,K)^T ----------------
// BM = 32*MI rows, 64 cols, 4 waves (2M x 2N), mfma_f32_16x16x32_bf16.
// AMODE 0: A bf16. AMODE 1: A[m][k] = b2f(Y[m*lda+k]) * silu(Z[m*ldz+k]) (both bf16).
// OMODE 0: f32 out. OMODE 1: bf16 out. K % 64 == 0, M % BM == 0.
template<int MI, int AMODE, int OMODE>
__global__ __launch_bounds__(256) void k_mm(
    const ushort* __restrict__ A, const ushort* __restrict__ Yp,
    const ushort* __restrict__ Zp, const ushort* __restrict__ Bt,
    void* __restrict__ Cp, int N, int K, int lda, int ldz, int ldc)
{
  __shared__ __align__(16) ushort As[32 * MI * 64];
  __shared__ __align__(16) ushort Bs[64 * 64];
  const int bm = blockIdx.y * (32 * MI), bn = blockIdx.x * 64;
  const int tid = threadIdx.x;
  const int l = tid & 63, w = tid >> 6;
  const int wm = w & 1, wn = w >> 1;
  f32x4 acc[MI][2] = {};

  for (int k0 = 0; k0 < K; k0 += 64) {
    #pragma unroll
    for (int p = 0; p < MI; p++) {
      int c = tid + p * 256;
      int row = c >> 3, ko = (c & 7) * 8;
      int sw = (row * 128 + (c & 7) * 16) ^ ((row & 7) << 4);
      if (AMODE == 0) {
        uint4 v = *(const uint4*)(A + (size_t)(bm + row) * lda + k0 + ko);
        *(uint4*)((char*)As + sw) = v;
      } else {
        const ushort* yrow = Yp + (size_t)(bm + row) * lda + k0 + ko;
        const ushort* zrow = Zp + (size_t)(bm + row) * ldz + k0 + ko;
        ushort tmp[8];
        #pragma unroll
        for (int j = 0; j < 8; j++) {
          float z = b2f(zrow[j]);
          tmp[j] = f2b(b2f(yrow[j]) * (z / (1.f + __expf(-z))));
        }
        *(uint4*)((char*)As + sw) = *(const uint4*)tmp;
      }
    }
    #pragma unroll
    for (int p = 0; p < 2; p++) {
      int c = tid + p * 256;
      int row = c >> 3, ko = (c & 7) * 8;
      int sw = (row * 128 + (c & 7) * 16) ^ ((row & 7) << 4);
      uint4 v = *(const uint4*)(Bt + (size_t)(bn + row) * K + k0 + ko);
      *(uint4*)((char*)Bs + sw) = v;
    }
    __syncthreads();
    #pragma unroll
    for (int ks = 0; ks < 2; ks++) {
      bf16x8 af[MI], bfv[2];
      #pragma unroll
      for (int mi = 0; mi < MI; mi++) {
        int r = 16 * MI * wm + 16 * mi + (l & 15);
        int ad = (r * 128 + 32 * ks + 16 * (l >> 4)) ^ ((r & 7) << 4);
        af[mi] = *(const bf16x8*)((const char*)As + ad);
      }
      #pragma unroll
      for (int ni = 0; ni < 2; ni++) {
        int r = 32 * wn + 16 * ni + (l & 15);
        int ad = (r * 128 + 32 * ks + 16 * (l >> 4)) ^ ((r & 7) << 4);
        bfv[ni] = *(const bf16x8*)((const char*)Bs + ad);
      }
      #pragma unroll
      for (int mi = 0; mi < MI; mi++)
        #pragma unroll
        for (int ni = 0; ni < 2; ni++)
          acc[mi][ni] = __builtin_amdgcn_mfma_f32_16x16x32_bf16(
              af[mi], bfv[ni], acc[mi][ni], 0, 0, 0);
    }
    __syncthreads();
  }

  #pragma unroll
  for (int mi = 0; mi < MI; mi++) {
    #pragma unroll
    for (int ni = 0; ni < 2; ni++) {
      int c0 = bn + 32 * wn + 16 * ni + (l & 15);
      if (c0 < N) {
        int r0 = bm + 16 * MI * wm + 16 * mi + 4 * (l >> 4);
        #pragma unroll
        for (int j = 0; j < 4; j++) {
          if (OMODE == 0)
            ((float*)Cp)[(size_t)(r0 + j) * ldc + c0] = acc[mi][ni][j];
          else
            ((ushort*)Cp)[(size_t)(r0 + j) * ldc + c0] = f2b(acc[mi][ni][j]);
        }
      }
    }
  }
}

// ---------------- causal depthwise conv + silu (bf16 in/out) ----------------
__global__ void k_conv(const ushort* __restrict__ XZ, int sgn,
                       const float* __restrict__ cw, const float* __restrict__ cb,
                       ushort* __restrict__ U) {
  int i = blockIdx.x * 256 + threadIdx.x;
  if (i >= LSEQ * DI) return;
  int t = i / DI, d = i % DI;
  float acc = cb[d];
  #pragma unroll
  for (int k = 0; k < DCONV; k++) {
    int r = (sgn > 0) ? (t - (DCONV-1) + k) : (t + (DCONV-1) - k);
    if (r >= 0 && r < LSEQ) acc += cw[d*DCONV + k] * b2f(XZ[(size_t)r*768 + d]);
  }
  U[i] = f2b(siluf(acc));
}

// ---------------- scan phase 1: fused dt, chunk-local scan + chunk product ----------------
__global__ __launch_bounds__(128) void k_scan1(const ushort* __restrict__ U,
                                               const float* __restrict__ PROJ,
                                               const float* __restrict__ Alog,
                                               const float* __restrict__ Wdt,
                                               const float* __restrict__ bdt,
                                               int sgn,
                                               float* __restrict__ Pc,
                                               float* __restrict__ Sc) {
  __shared__ float Ps[TCH][NPROJ];
  int c = blockIdx.y;
  int d = blockIdx.x * 128 + threadIdx.x;
  for (int j = threadIdx.x; j < TCH * 11; j += 128) {
    int row = j / 11, q4 = j % 11;
    int s = c*TCH + row;
    int rg = (sgn > 0) ? s : (LSEQ-1-s);
    *(float4*)&Ps[row][q4*4] = *(const float4*)(PROJ + (size_t)rg*NPROJ + q4*4);
  }
  __syncthreads();

  float wdt[DTRK];
  #pragma unroll
  for (int k = 0; k < DTRK; k++) wdt[k] = Wdt[k*DI + d];
  float bdtv = bdt[d];
  float A[DSN]; bool fast = true;
  #pragma unroll
  for (int n = 0; n < DSN; n++) {
    A[n] = -__expf(Alog[d*DSN + n]);
    fast = fast && (fabsf(A[n] + (float)(n+1)) <= 1e-3f * (n+1));
  }
  float S[DSN] = {};
  float dtsum = 0.f;
  for (int t = 0; t < TCH; t++) {
    int s = c*TCH + t;
    int row = (sgn > 0) ? s : (LSEQ-1-s);
    float u = b2f(U[(size_t)row*DI + d]);
    float xdt = bdtv;
    #pragma unroll
    for (int k = 0; k < DTRK; k++) xdt += Ps[t][k] * wdt[k];
    float dtv = softplus_f(xdt);
    float du = dtv * u;
    dtsum += dtv;
    float a[DSN];
    if (fast) { pow16(__expf(-dtv), a); }
    else {
      #pragma unroll
      for (int n = 0; n < DSN; n++) a[n] = __expf(dtv * A[n]);
    }
    #pragma unroll
    for (int n = 0; n < DSN; n++)
      S[n] = a[n] * S[n] + du * Ps[t][DTRK + n];
  }
  float P[DSN];
  if (fast) { pow16(__expf(-dtsum), P); }
  else {
    #pragma unroll
    for (int n = 0; n < DSN; n++) P[n] = __expf(A[n] * dtsum);
  }
  size_t base = (size_t)c * GDIM + (size_t)d * DSN;
  #pragma unroll
  for (int n = 0; n < DSN; n++) { Pc[base + n] = P[n]; Sc[base + n] = S[n]; }
}

// ---------------- scan 2a: compose 8-chunk groups (parallel) ----------------
__global__ __launch_bounds__(256) void k_scan2a(const float* __restrict__ Pc,
                                                const float* __restrict__ Sc,
                                                float* __restrict__ PL,
                                                float* __restrict__ SL) {
  int g = blockIdx.x * 256 + threadIdx.x;
  int l = blockIdx.y;
  float Pa = 1.f, Sa = 0.f;
  #pragma unroll
  for (int j = 0; j < RGRP; j++) {
    size_t o = (size_t)(l*RGRP + j) * GDIM + g;
    float p = Pc[o], s = Sc[o];
    Sa = fmaf(p, Sa, s);
    Pa *= p;
  }
  PL[(size_t)l * GDIM + g] = Pa;
  SL[(size_t)l * GDIM + g] = Sa;
}

// ---------------- scan 2b: serial scan over 64 group summaries ----------------
__global__ __launch_bounds__(256) void k_scan2b(const float* __restrict__ PL,
                                                const float* __restrict__ SL,
                                                float* __restrict__ HL) {
  int g = blockIdx.x * 256 + threadIdx.x;
  float p[NGRP], s[NGRP];
  #pragma unroll
  for (int l = 0; l < NGRP; l++) {
    p[l] = PL[(size_t)l * GDIM + g];
    s[l] = SL[(size_t)l * GDIM + g];
  }
  float H = 0.f;
  #pragma unroll
  for (int l = 0; l < NGRP; l++) {
    HL[(size_t)l * GDIM + g] = H;
    H = fmaf(p[l], H, s[l]);
  }
}

// ---------------- scan 2c: expand group states to per-chunk init states ----------------
__global__ __launch_bounds__(256) void k_scan2c(const float* __restrict__ Pc,
                                                const float* __restrict__ Sc,
                                                const float* __restrict__ HL,
                                                float* __restrict__ Hc) {
  int g = blockIdx.x * 256 + threadIdx.x;
  int l = blockIdx.y;
  float h = HL[(size_t)l * GDIM + g];
  #pragma unroll
  for (int j = 0; j < RGRP; j++) {
    size_t o = (size_t)(l*RGRP + j) * GDIM + g;
    Hc[o] = h;
    h = fmaf(Pc[o], h, Sc[o]);
  }
}

// ---------------- scan phase 3: fused dt, rescan with init state, emit y (bf16) ----------------
__global__ __launch_bounds__(128) void k_scan3(const ushort* __restrict__ U,
                                               const float* __restrict__ PROJ,
                                               const float* __restrict__ Alog,
                                               const float* __restrict__ Wdt,
                                               const float* __restrict__ bdt,
                                               const float* __restrict__ Dp,
                                               const float* __restrict__ Hc,
                                               int sgn,
                                               ushort* __restrict__ Y /* ld 384, bf16 */) {
  __shared__ float Ps[TCH][NPROJ];
  int c = blockIdx.y;
  int d = blockIdx.x * 128 + threadIdx.x;
  for (int j = threadIdx.x; j < TCH * 11; j += 128) {
    int row = j / 11, q4 = j % 11;
    int s = c*TCH + row;
    int rg = (sgn > 0) ? s : (LSEQ-1-s);
    *(float4*)&Ps[row][q4*4] = *(const float4*)(PROJ + (size_t)rg*NPROJ + q4*4);
  }
  __syncthreads();

  float wdt[DTRK];
  #pragma unroll
  for (int k = 0; k < DTRK; k++) wdt[k] = Wdt[k*DI + d];
  float bdtv = bdt[d];
  float A[DSN]; bool fast = true;
  #pragma unroll
  for (int n = 0; n < DSN; n++) {
    A[n] = -__expf(Alog[d*DSN + n]);
    fast = fast && (fabsf(A[n] + (float)(n+1)) <= 1e-3f * (n+1));
  }
  float h[DSN];
  size_t hb = (size_t)c * GDIM + (size_t)d * DSN;
  #pragma unroll
  for (int n = 0; n < DSN; n++) h[n] = Hc[hb + n];
  float dskip = Dp[d];

  for (int t = 0; t < TCH; t++) {
    int s = c*TCH + t;
    int row = (sgn > 0) ? s : (LSEQ-1-s);
    float u = b2f(U[(size_t)row*DI + d]);
    float xdt = bdtv;
    #pragma unroll
    for (int k = 0; k < DTRK; k++) xdt += Ps[t][k] * wdt[k];
    float dtv = softplus_f(xdt);
    float du = dtv * u;
    float a[DSN];
    if (fast) { pow16(__expf(-dtv), a); }
    else {
      #pragma unroll
      for (int n = 0; n < DSN; n++) a[n] = __expf(dtv * A[n]);
    }
    float y = u * dskip;
    #pragma unroll
    for (int n = 0; n < DSN; n++) {
      h[n] = a[n] * h[n] + du * Ps[t][DTRK + n];
      y += h[n] * Ps[t][DTRK + DSN + n];
    }
    Y[(size_t)row * DI + d] = f2b(y);
  }
}

// ---------------- final combine ----------------
__device__ __forceinline__ void ln_row(float (&v)[3], const float* __restrict__ w,
                                       const float* __restrict__ b, int lane) {
  float s = v[0] + v[1] + v[2];
  #pragma unroll
  for (int o = 32; o > 0; o >>= 1) s += __shfl_xor(s, o);
  float m = s * (1.f / DM);
  float q = 0.f;
  #pragma unroll
  for (int i = 0; i < 3; i++) { float d = v[i] - m; q += d*d; }
  #pragma unroll
  for (int o = 32; o > 0; o >>= 1) q += __shfl_xor(q, o);
  float inv = rsqrtf(q * (1.f / DM) + EPSV);
  #pragma unroll
  for (int i = 0; i < 3; i++) v[i] = (v[i] - m) * inv * w[lane + 64*i] + b[lane + 64*i];
}

// FIRST=1: out = x + cb (covers all rows; idx is a permutation). FIRST=0: out += cb.
template<int FIRST>
__global__ __launch_bounds__(64) void k_final(const float* __restrict__ x,
                                              const int* __restrict__ idx,
                                              const float* __restrict__ G4f,
                                              const float* __restrict__ G4b,
                                              const float* __restrict__ lnfw,
                                              const float* __restrict__ lnfb,
                                              const float* __restrict__ lnbw,
                                              const float* __restrict__ lnbb,
                                              const float* __restrict__ lnow,
                                              const float* __restrict__ lnob,
                                              float* __restrict__ out) {
  int t = blockIdx.x, lane = threadIdx.x;
  int r = idx[t];
  float f[3], g[3], cb[3];
  #pragma unroll
  for (int i = 0; i < 3; i++) {
    int j = lane + 64*i;
    float xo = x[(size_t)r*DM + j];
    f[i] = xo + G4f[(size_t)t*DM + j];
    g[i] = xo + G4b[(size_t)t*DM + j];
  }
  ln_row(f, lnfw, lnfb, lane);
  ln_row(g, lnbw, lnbb, lane);
  #pragma unroll
  for (int i = 0; i < 3; i++) cb[i] = f[i] + g[i];
  ln_row(cb, lnow, lnob, lane);
  #pragma unroll
  for (int i = 0; i < 3; i++) {
    int j = lane + 64*i;
    if (FIRST)
      out[(size_t)r*DM + j] = x[(size_t)r*DM + j] + cb[i];
    else
      out[(size_t)r*DM + j] += cb[i];
  }
}

extern "C" void kernel_launch(void* const* d_in, const int* in_sizes, int n_in,
                              void* d_out, int out_size, void* d_ws, size_t ws_size,
                              hipStream_t stream) {
  const float* x      = (const float*)d_in[0];
  const int*   orders = (const int*)  d_in[1];
  const float* nw     = (const float*)d_in[2];
  const float* Wi     = (const float*)d_in[3];
  const float* cw     = (const float*)d_in[4];
  const float* cbi    = (const float*)d_in[5];
  const float* Wx     = (const float*)d_in[6];
  const float* Wdt    = (const float*)d_in[7];
  const float* bdt    = (const float*)d_in[8];
  const float* Alog   = (const float*)d_in[9];
  const float* Dp     = (const float*)d_in[10];
  const float* Wo     = (const float*)d_in[11];
  const float* flw    = (const float*)d_in[12];
  const float* flb    = (const float*)d_in[13];
  const float* blw    = (const float*)d_in[14];
  const float* blb    = (const float*)d_in[15];
  const float* olw    = (const float*)d_in[16];
  const float* olb    = (const float*)d_in[17];
  float* outp = (float*)d_out;

  char* w = (char*)d_ws;
  size_t off = 0;
  auto take = [&](size_t bytes) -> void* {
    char* p = w + off;
    off += (bytes + 255) & ~(size_t)255;
    return (void*)p;
  };
  ushort* Wct  = (ushort*)take((size_t)4 * 768 * DM * 2);
  ushort* Wxt  = (ushort*)take((size_t)4 * 64 * DI * 2);
  ushort* Wot  = (ushort*)take((size_t)4 * DM * DI * 2);
  ushort* xon  = (ushort*)take((size_t)LSEQ * DM * 2);
  ushort* xz   = (ushort*)take((size_t)LSEQ * 768 * 2);
  ushort* uc   = (ushort*)take((size_t)LSEQ * DI * 2);
  ushort* ybuf = (ushort*)take((size_t)LSEQ * DI * 2);
  float*  proj = (float*) take((size_t)LSEQ * NPROJ * 4);
  float*  g4f  = (float*) take((size_t)LSEQ * DM * 4);
  float*  g4b  = (float*) take((size_t)LSEQ * DM * 4);
  float*  Pc   = (float*) take((size_t)NCH * GDIM * 4);
  float*  Sc   = (float*) take((size_t)NCH * GDIM * 4);
  float*  Hc   = (float*) take((size_t)NCH * GDIM * 4);
  float*  PL   = (float*) take((size_t)NGRP * GDIM * 4);
  float*  SL   = (float*) take((size_t)NGRP * GDIM * 4);
  float*  HL   = (float*) take((size_t)NGRP * GDIM * 4);
  (void)ws_size; (void)n_in; (void)in_sizes; (void)out_size;

  // weight prep, all 4 blocks, once
  k_prep<<<(PREP_A + PREP_B + PREP_C + 255)/256, 256, 0, stream>>>(
      Wi, nw, Wx, Wo, Wct, Wxt, Wot);

  for (int o = 0; o < 2; o++) {
    const int* idx = orders + (size_t)o * LSEQ;
    k_gather_rms<<<LSEQ, 64, 0, stream>>>(x, idx, xon);

    for (int dir = 0; dir < 2; dir++) {
      int blk = (dir == 0) ? o : 2 + o;
      int sgn = (dir == 0) ? 1 : -1;
      float* g4 = (dir == 0) ? g4f : g4b;

      // in-proj: xz(bf16, ld 768) = xon @ Wc
      k_mm<4,0,1><<<dim3(768/64, LSEQ/128), 256, 0, stream>>>(
          xon, nullptr, nullptr, Wct + (size_t)blk*768*DM, xz, 768, DM, DM, 0, 768);
      // conv
      k_conv<<<(LSEQ*DI + 255)/256, 256, 0, stream>>>(
          xz, sgn, cw + (size_t)blk*DI*DCONV, cbi + (size_t)blk*DI, uc);
      // x-proj: proj(f32, ld 44) = uc @ Wx
      k_mm<2,0,0><<<dim3(1, LSEQ/64), 256, 0, stream>>>(
          uc, nullptr, nullptr, Wxt + (size_t)blk*64*DI, proj, NPROJ, DI, DI, 0, NPROJ);
      // scans (dt fused)
      k_scan1<<<dim3(DI/128, NCH), 128, 0, stream>>>(
          uc, proj, Alog + (size_t)blk*DI*DSN, Wdt + (size_t)blk*DTRK*DI,
          bdt + (size_t)blk*DI, sgn, Pc, Sc);
      k_scan2a<<<dim3(GDIM/256, NGRP), 256, 0, stream>>>(Pc, Sc, PL, SL);
      k_scan2b<<<GDIM/256, 256, 0, stream>>>(PL, SL, HL);
      k_scan2c<<<dim3(GDIM/256, NGRP), 256, 0, stream>>>(Pc, Sc, HL, Hc);
      k_scan3<<<dim3(DI/128, NCH), 128, 0, stream>>>(
          uc, proj, Alog + (size_t)blk*DI*DSN, Wdt + (size_t)blk*DTRK*DI,
          bdt + (size_t)blk*DI, Dp + (size_t)blk*DI, Hc, sgn, ybuf);
      // out-proj: g4(f32, ld 192) = (y * silu(z)) @ Wo
      k_mm<2,1,0><<<dim3(DM/64, LSEQ/64), 256, 0, stream>>>(
          nullptr, ybuf, xz + 384, Wot + (size_t)blk*DM*DI, g4, DM, DI, DI, 768, DM);
    }
    if (o == 0)
      k_final<1><<<LSEQ, 64, 0, stream>>>(x, idx, g4f, g4b,
          flw, flb, blw, blb, olw, olb, outp);
    else
      k_final<0><<<LSEQ, 64, 0, stream>>>(x, idx, g4f, g4b,
          flw + (size_t)DM, flb + (size_t)DM,
          blw + (size_t)DM, blb + (size_t)DM,
          olw + (size_t)DM, olb + (size_t)DM, outp);
  }
}

// Round 5
// 536.640 us; speedup vs baseline: 2.9067x; 1.1726x over previous
//
#include <hip/hip_runtime.h>
#include <math.h>

#define LSEQ 16384
#define DM 192
#define DI 384
#define DSN 16
#define DCONV 4
#define DTRK 12
#define NPROJ 44   /* DTRK + 2*DSN */
#define EPSV 1e-5f
#define TCH 32
#define NCH (LSEQ / TCH)          /* 512 chunks */
#define GDIM (DI * DSN)           /* 6144 sequences */
#define RGRP 8                    /* chunks per group */
#define NGRP (NCH / RGRP)         /* 64 groups */

typedef __attribute__((ext_vector_type(8))) short bf16x8;
typedef __attribute__((ext_vector_type(4))) float f32x4;

__device__ __forceinline__ float siluf(float x) { return x / (1.f + __expf(-x)); }
__device__ __forceinline__ float softplus_f(float x) {
  float e = __expf(x);
  float l = __logf(1.f + e);
  return (x > 20.f) ? x : l;
}
__device__ __forceinline__ ushort f2b(float f) {
  uint u = __float_as_uint(f);
  u += 0x7fff + ((u >> 16) & 1);
  return (ushort)(u >> 16);
}
__device__ __forceinline__ float b2f(ushort h) { return __uint_as_float(((uint)h) << 16); }

// a[n] = q^(n+1), log-depth
__device__ __forceinline__ void pow16(float q, float (&a)[16]) {
  float q2 = q*q, q4 = q2*q2, q8 = q4*q4;
  a[0]=q;        a[1]=q2;       a[2]=q2*q;      a[3]=q4;
  a[4]=q4*q;     a[5]=q4*q2;    a[6]=q4*q2*q;   a[7]=q8;
  a[8]=q8*q;     a[9]=q8*q2;    a[10]=q8*q2*q;  a[11]=q8*q4;
  a[12]=q8*q4*q; a[13]=q8*q4*q2;a[14]=q8*q4*q2*q;a[15]=q8*q8;
}

// ---------------- unified weight prep (all 4 blocks) ----------------
#define PREP_A (4 * 768 * DM)
#define PREP_B (4 * 64 * DI)
#define PREP_C (4 * DM * DI)
__global__ void k_prep(const float* __restrict__ Wi, const float* __restrict__ nw,
                       const float* __restrict__ Wx, const float* __restrict__ Wo,
                       ushort* __restrict__ Wct, ushort* __restrict__ Wxt,
                       ushort* __restrict__ Wot) {
  int i = blockIdx.x * 256 + threadIdx.x;
  if (i < PREP_A) {
    int blk = i / (768 * DM), j = i % (768 * DM);
    int n = j / DM, k = j % DM;
    Wct[i] = f2b(nw[blk*DM + k] * Wi[(size_t)blk*DM*768 + (size_t)k*768 + n]);
  } else if (i < PREP_A + PREP_B) {
    int q = i - PREP_A;
    int blk = q / (64 * DI), j = q % (64 * DI);
    int n = j / DI, k = j % DI;
    Wxt[q] = (n < NPROJ) ? f2b(Wx[(size_t)blk*DI*NPROJ + (size_t)k*NPROJ + n]) : (ushort)0;
  } else if (i < PREP_A + PREP_B + PREP_C) {
    int q = i - PREP_A - PREP_B;
    int blk = q / (DM * DI), j = q % (DM * DI);
    int n = j / DI, k = j % DI;
    Wot[q] = f2b(Wo[(size_t)blk*DI*DM + (size_t)k*DM + n]);
  }
}

// ---------------- gather + rmsnorm -> bf16 (both orders, z = order) ----------------
__global__ __launch_bounds__(64) void k_gather_rms(const float* __restrict__ x,
                                                   const int* __restrict__ orders,
                                                   ushort* __restrict__ xon) {
  int t = blockIdx.x;
  int o = blockIdx.y;
  int lane = threadIdx.x;
  int r = orders[(size_t)o*LSEQ + t];
  ushort* xo = xon + (size_t)o*LSEQ*DM;
  float v0 = x[(size_t)r*DM + lane];
  float v1 = x[(size_t)r*DM + 64 + lane];
  float v2 = x[(size_t)r*DM + 128 + lane];
  float ss = v0*v0 + v1*v1 + v2*v2;
  #pragma unroll
  for (int oo = 32; oo > 0; oo >>= 1) ss += __shfl_xor(ss, oo);
  float s = rsqrtf(ss * (1.f/DM) + EPSV);
  xo[(size_t)t*DM + lane]       = f2b(v0 * s);
  xo[(size_t)t*DM + 64 + lane]  = f2b(v1 * s);
  xo[(size_t)t*DM + 128 + lane] = f2b(v2 * s);
}

// ---------------- MFMA GEMM, z-batched: C(MxN) = A(MxK) @ Bt(N,K)^T ----------------
// BM = 32*MI rows, 64 cols, 4 waves, mfma_f32_16x16x32_bf16.
// AMODE 0: A bf16. AMODE 1: A[m][k] = b2f(Y) * silu(b2f(Z)).
// OMODE 0: f32 out (C0). OMODE 1: bf16 out (C0). OMODE 2: bf16 split at col 384 (C0/C1, ld 384).
template<int MI, int AMODE, int OMODE>
__global__ __launch_bounds__(256) void k_mm(
    const ushort* __restrict__ A, const ushort* __restrict__ Yp,
    const ushort* __restrict__ Zp, const ushort* __restrict__ Bt,
    void* __restrict__ C0, void* __restrict__ C1,
    int N, int K, int lda, int ldz, int ldc,
    long sA, long sY, long sZ, long sB, long sC)
{
  __shared__ __align__(16) ushort As[32 * MI * 64];
  __shared__ __align__(16) ushort Bs[64 * 64];
  const int z = blockIdx.z;
  if (AMODE == 0) A += (size_t)z * sA;
  else { Yp += (size_t)z * sY; Zp += (size_t)z * sZ; }
  Bt += (size_t)z * sB;
  const int bm = blockIdx.y * (32 * MI), bn = blockIdx.x * 64;
  const int tid = threadIdx.x;
  const int l = tid & 63, w = tid >> 6;
  const int wm = w & 1, wn = w >> 1;
  f32x4 acc[MI][2] = {};

  for (int k0 = 0; k0 < K; k0 += 64) {
    #pragma unroll
    for (int p = 0; p < MI; p++) {
      int c = tid + p * 256;
      int row = c >> 3, ko = (c & 7) * 8;
      int sw = (row * 128 + (c & 7) * 16) ^ ((row & 7) << 4);
      if (AMODE == 0) {
        uint4 v = *(const uint4*)(A + (size_t)(bm + row) * lda + k0 + ko);
        *(uint4*)((char*)As + sw) = v;
      } else {
        const ushort* yrow = Yp + (size_t)(bm + row) * lda + k0 + ko;
        const ushort* zrow = Zp + (size_t)(bm + row) * ldz + k0 + ko;
        ushort tmp[8];
        #pragma unroll
        for (int j = 0; j < 8; j++) {
          float zz = b2f(zrow[j]);
          tmp[j] = f2b(b2f(yrow[j]) * (zz / (1.f + __expf(-zz))));
        }
        *(uint4*)((char*)As + sw) = *(const uint4*)tmp;
      }
    }
    #pragma unroll
    for (int p = 0; p < 2; p++) {
      int c = tid + p * 256;
      int row = c >> 3, ko = (c & 7) * 8;
      int sw = (row * 128 + (c & 7) * 16) ^ ((row & 7) << 4);
      uint4 v = *(const uint4*)(Bt + (size_t)(bn + row) * K + k0 + ko);
      *(uint4*)((char*)Bs + sw) = v;
    }
    __syncthreads();
    #pragma unroll
    for (int ks = 0; ks < 2; ks++) {
      bf16x8 af[MI], bfv[2];
      #pragma unroll
      for (int mi = 0; mi < MI; mi++) {
        int r = 16 * MI * wm + 16 * mi + (l & 15);
        int ad = (r * 128 + 32 * ks + 16 * (l >> 4)) ^ ((r & 7) << 4);
        af[mi] = *(const bf16x8*)((const char*)As + ad);
      }
      #pragma unroll
      for (int ni = 0; ni < 2; ni++) {
        int r = 32 * wn + 16 * ni + (l & 15);
        int ad = (r * 128 + 32 * ks + 16 * (l >> 4)) ^ ((r & 7) << 4);
        bfv[ni] = *(const bf16x8*)((const char*)Bs + ad);
      }
      #pragma unroll
      for (int mi = 0; mi < MI; mi++)
        #pragma unroll
        for (int ni = 0; ni < 2; ni++)
          acc[mi][ni] = __builtin_amdgcn_mfma_f32_16x16x32_bf16(
              af[mi], bfv[ni], acc[mi][ni], 0, 0, 0);
    }
    __syncthreads();
  }

  #pragma unroll
  for (int mi = 0; mi < MI; mi++) {
    #pragma unroll
    for (int ni = 0; ni < 2; ni++) {
      int c0 = bn + 32 * wn + 16 * ni + (l & 15);
      if (OMODE != 2 && c0 >= N) continue;
      int r0 = bm + 16 * MI * wm + 16 * mi + 4 * (l >> 4);
      #pragma unroll
      for (int j = 0; j < 4; j++) {
        if (OMODE == 0) {
          ((float*)C0 + (size_t)z*sC)[(size_t)(r0 + j) * ldc + c0] = acc[mi][ni][j];
        } else if (OMODE == 1) {
          ((ushort*)C0 + (size_t)z*sC)[(size_t)(r0 + j) * ldc + c0] = f2b(acc[mi][ni][j]);
        } else {
          // split at column 384 (bn is 64-aligned so the side is block-uniform)
          if (c0 < 384)
            ((ushort*)C0 + (size_t)z*sC)[(size_t)(r0 + j) * 384 + c0] = f2b(acc[mi][ni][j]);
          else
            ((ushort*)C1 + (size_t)z*sC)[(size_t)(r0 + j) * 384 + (c0 - 384)] = f2b(acc[mi][ni][j]);
        }
      }
    }
  }
}

// ---------------- causal depthwise conv + silu, z = dir ----------------
__global__ void k_conv(const ushort* __restrict__ XC,
                       const float* __restrict__ cw, const float* __restrict__ cb,
                       ushort* __restrict__ U, int o) {
  int z = blockIdx.y;
  int i = blockIdx.x * 256 + threadIdx.x;
  if (i >= LSEQ * DI) return;
  int t = i / DI, d = i % DI;
  int blk = o + 2*z;
  int sgn = 1 - 2*z;
  const ushort* X = XC + (size_t)z*LSEQ*DI;
  float acc = cb[blk*DI + d];
  #pragma unroll
  for (int k = 0; k < DCONV; k++) {
    int r = (sgn > 0) ? (t - (DCONV-1) + k) : (t + (DCONV-1) - k);
    if (r >= 0 && r < LSEQ) acc += cw[(size_t)blk*DI*DCONV + d*DCONV + k] * b2f(X[(size_t)r*DI + d]);
  }
  U[(size_t)z*LSEQ*DI + i] = f2b(siluf(acc));
}

// ---------------- scan phase 1, z = dir ----------------
__global__ __launch_bounds__(128) void k_scan1(const ushort* __restrict__ U,
                                               const float* __restrict__ PROJ,
                                               const float* __restrict__ Alog,
                                               const float* __restrict__ Wdt,
                                               const float* __restrict__ bdt,
                                               float* __restrict__ Pc,
                                               float* __restrict__ Sc, int o) {
  __shared__ float Ps[TCH][NPROJ];
  int z = blockIdx.z;
  int blk = o + 2*z;
  int sgn = 1 - 2*z;
  const ushort* Uz = U + (size_t)z*LSEQ*DI;
  const float* Pz = PROJ + (size_t)z*LSEQ*NPROJ;
  int c = blockIdx.y;
  int d = blockIdx.x * 128 + threadIdx.x;
  for (int j = threadIdx.x; j < TCH * 11; j += 128) {
    int row = j / 11, q4 = j % 11;
    int s = c*TCH + row;
    int rg = (sgn > 0) ? s : (LSEQ-1-s);
    *(float4*)&Ps[row][q4*4] = *(const float4*)(Pz + (size_t)rg*NPROJ + q4*4);
  }
  __syncthreads();

  float wdt[DTRK];
  #pragma unroll
  for (int k = 0; k < DTRK; k++) wdt[k] = Wdt[(size_t)blk*DTRK*DI + k*DI + d];
  float bdtv = bdt[blk*DI + d];
  float A[DSN]; bool fast = true;
  #pragma unroll
  for (int n = 0; n < DSN; n++) {
    A[n] = -__expf(Alog[(size_t)blk*DI*DSN + d*DSN + n]);
    fast = fast && (fabsf(A[n] + (float)(n+1)) <= 1e-3f * (n+1));
  }
  float S[DSN] = {};
  float dtsum = 0.f;
  for (int t = 0; t < TCH; t++) {
    int s = c*TCH + t;
    int row = (sgn > 0) ? s : (LSEQ-1-s);
    float u = b2f(Uz[(size_t)row*DI + d]);
    float xdt = bdtv;
    #pragma unroll
    for (int k = 0; k < DTRK; k++) xdt += Ps[t][k] * wdt[k];
    float dtv = softplus_f(xdt);
    float du = dtv * u;
    dtsum += dtv;
    float a[DSN];
    if (fast) { pow16(__expf(-dtv), a); }
    else {
      #pragma unroll
      for (int n = 0; n < DSN; n++) a[n] = __expf(dtv * A[n]);
    }
    #pragma unroll
    for (int n = 0; n < DSN; n++)
      S[n] = a[n] * S[n] + du * Ps[t][DTRK + n];
  }
  float P[DSN];
  if (fast) { pow16(__expf(-dtsum), P); }
  else {
    #pragma unroll
    for (int n = 0; n < DSN; n++) P[n] = __expf(A[n] * dtsum);
  }
  size_t base = (size_t)z*NCH*GDIM + (size_t)c * GDIM + (size_t)d * DSN;
  #pragma unroll
  for (int n = 0; n < DSN; n++) { Pc[base + n] = P[n]; Sc[base + n] = S[n]; }
}

// ---------------- scan 2a ----------------
__global__ __launch_bounds__(256) void k_scan2a(const float* __restrict__ Pc,
                                                const float* __restrict__ Sc,
                                                float* __restrict__ PL,
                                                float* __restrict__ SL) {
  int g = blockIdx.x * 256 + threadIdx.x;
  int l = blockIdx.y;
  int z = blockIdx.z;
  const float* Pz = Pc + (size_t)z*NCH*GDIM;
  const float* Sz = Sc + (size_t)z*NCH*GDIM;
  float Pa = 1.f, Sa = 0.f;
  #pragma unroll
  for (int j = 0; j < RGRP; j++) {
    size_t off = (size_t)(l*RGRP + j) * GDIM + g;
    float p = Pz[off], s = Sz[off];
    Sa = fmaf(p, Sa, s);
    Pa *= p;
  }
  PL[(size_t)z*NGRP*GDIM + (size_t)l * GDIM + g] = Pa;
  SL[(size_t)z*NGRP*GDIM + (size_t)l * GDIM + g] = Sa;
}

// ---------------- scan 2b ----------------
__global__ __launch_bounds__(256) void k_scan2b(const float* __restrict__ PL,
                                                const float* __restrict__ SL,
                                                float* __restrict__ HL) {
  int g = blockIdx.x * 256 + threadIdx.x;
  int z = blockIdx.y;
  const float* Pz = PL + (size_t)z*NGRP*GDIM;
  const float* Sz = SL + (size_t)z*NGRP*GDIM;
  float* Hz = HL + (size_t)z*NGRP*GDIM;
  float p[NGRP], s[NGRP];
  #pragma unroll
  for (int l = 0; l < NGRP; l++) {
    p[l] = Pz[(size_t)l * GDIM + g];
    s[l] = Sz[(size_t)l * GDIM + g];
  }
  float H = 0.f;
  #pragma unroll
  for (int l = 0; l < NGRP; l++) {
    Hz[(size_t)l * GDIM + g] = H;
    H = fmaf(p[l], H, s[l]);
  }
}

// ---------------- scan 2c ----------------
__global__ __launch_bounds__(256) void k_scan2c(const float* __restrict__ Pc,
                                                const float* __restrict__ Sc,
                                                const float* __restrict__ HL,
                                                float* __restrict__ Hc) {
  int g = blockIdx.x * 256 + threadIdx.x;
  int l = blockIdx.y;
  int z = blockIdx.z;
  const float* Pz = Pc + (size_t)z*NCH*GDIM;
  const float* Sz = Sc + (size_t)z*NCH*GDIM;
  float h = HL[(size_t)z*NGRP*GDIM + (size_t)l * GDIM + g];
  float* Hz = Hc + (size_t)z*NCH*GDIM;
  #pragma unroll
  for (int j = 0; j < RGRP; j++) {
    size_t off = (size_t)(l*RGRP + j) * GDIM + g;
    Hz[off] = h;
    h = fmaf(Pz[off], h, Sz[off]);
  }
}

// ---------------- scan phase 3, z = dir ----------------
__global__ __launch_bounds__(128) void k_scan3(const ushort* __restrict__ U,
                                               const float* __restrict__ PROJ,
                                               const float* __restrict__ Alog,
                                               const float* __restrict__ Wdt,
                                               const float* __restrict__ bdt,
                                               const float* __restrict__ Dp,
                                               const float* __restrict__ Hc,
                                               ushort* __restrict__ Y, int o) {
  __shared__ float Ps[TCH][NPROJ];
  int z = blockIdx.z;
  int blk = o + 2*z;
  int sgn = 1 - 2*z;
  const ushort* Uz = U + (size_t)z*LSEQ*DI;
  const float* Pz = PROJ + (size_t)z*LSEQ*NPROJ;
  ushort* Yz = Y + (size_t)z*LSEQ*DI;
  int c = blockIdx.y;
  int d = blockIdx.x * 128 + threadIdx.x;
  for (int j = threadIdx.x; j < TCH * 11; j += 128) {
    int row = j / 11, q4 = j % 11;
    int s = c*TCH + row;
    int rg = (sgn > 0) ? s : (LSEQ-1-s);
    *(float4*)&Ps[row][q4*4] = *(const float4*)(Pz + (size_t)rg*NPROJ + q4*4);
  }
  __syncthreads();

  float wdt[DTRK];
  #pragma unroll
  for (int k = 0; k < DTRK; k++) wdt[k] = Wdt[(size_t)blk*DTRK*DI + k*DI + d];
  float bdtv = bdt[blk*DI + d];
  float A[DSN]; bool fast = true;
  #pragma unroll
  for (int n = 0; n < DSN; n++) {
    A[n] = -__expf(Alog[(size_t)blk*DI*DSN + d*DSN + n]);
    fast = fast && (fabsf(A[n] + (float)(n+1)) <= 1e-3f * (n+1));
  }
  float h[DSN];
  size_t hb = (size_t)z*NCH*GDIM + (size_t)c * GDIM + (size_t)d * DSN;
  #pragma unroll
  for (int n = 0; n < DSN; n++) h[n] = Hc[hb + n];
  float dskip = Dp[blk*DI + d];

  for (int t = 0; t < TCH; t++) {
    int s = c*TCH + t;
    int row = (sgn > 0) ? s : (LSEQ-1-s);
    float u = b2f(Uz[(size_t)row*DI + d]);
    float xdt = bdtv;
    #pragma unroll
    for (int k = 0; k < DTRK; k++) xdt += Ps[t][k] * wdt[k];
    float dtv = softplus_f(xdt);
    float du = dtv * u;
    float a[DSN];
    if (fast) { pow16(__expf(-dtv), a); }
    else {
      #pragma unroll
      for (int n = 0; n < DSN; n++) a[n] = __expf(dtv * A[n]);
    }
    float y = u * dskip;
    #pragma unroll
    for (int n = 0; n < DSN; n++) {
      h[n] = a[n] * h[n] + du * Ps[t][DTRK + n];
      y += h[n] * Ps[t][DTRK + DSN + n];
    }
    Yz[(size_t)row * DI + d] = f2b(y);
  }
}

// ---------------- final combine ----------------
__device__ __forceinline__ void ln_row(float (&v)[3], const float* __restrict__ w,
                                       const float* __restrict__ b, int lane) {
  float s = v[0] + v[1] + v[2];
  #pragma unroll
  for (int o = 32; o > 0; o >>= 1) s += __shfl_xor(s, o);
  float m = s * (1.f / DM);
  float q = 0.f;
  #pragma unroll
  for (int i = 0; i < 3; i++) { float d = v[i] - m; q += d*d; }
  #pragma unroll
  for (int o = 32; o > 0; o >>= 1) q += __shfl_xor(q, o);
  float inv = rsqrtf(q * (1.f / DM) + EPSV);
  #pragma unroll
  for (int i = 0; i < 3; i++) v[i] = (v[i] - m) * inv * w[lane + 64*i] + b[lane + 64*i];
}

// FIRST=1: out = x + cb (idx is a permutation). FIRST=0: out += cb.
template<int FIRST>
__global__ __launch_bounds__(64) void k_final(const float* __restrict__ x,
                                              const int* __restrict__ idx,
                                              const ushort* __restrict__ G4f,
                                              const ushort* __restrict__ G4b,
                                              const float* __restrict__ lnfw,
                                              const float* __restrict__ lnfb,
                                              const float* __restrict__ lnbw,
                                              const float* __restrict__ lnbb,
                                              const float* __restrict__ lnow,
                                              const float* __restrict__ lnob,
                                              float* __restrict__ out) {
  int t = blockIdx.x, lane = threadIdx.x;
  int r = idx[t];
  float f[3], g[3], cb[3];
  #pragma unroll
  for (int i = 0; i < 3; i++) {
    int j = lane + 64*i;
    float xo = x[(size_t)r*DM + j];
    f[i] = xo + b2f(G4f[(size_t)t*DM + j]);
    g[i] = xo + b2f(G4b[(size_t)t*DM + j]);
  }
  ln_row(f, lnfw, lnfb, lane);
  ln_row(g, lnbw, lnbb, lane);
  #pragma unroll
  for (int i = 0; i < 3; i++) cb[i] = f[i] + g[i];
  ln_row(cb, lnow, lnob, lane);
  #pragma unroll
  for (int i = 0; i < 3; i++) {
    int j = lane + 64*i;
    if (FIRST)
      out[(size_t)r*DM + j] = x[(size_t)r*DM + j] + cb[i];
    else
      out[(size_t)r*DM + j] += cb[i];
  }
}

extern "C" void kernel_launch(void* const* d_in, const int* in_sizes, int n_in,
                              void* d_out, int out_size, void* d_ws, size_t ws_size,
                              hipStream_t stream) {
  const float* x      = (const float*)d_in[0];
  const int*   orders = (const int*)  d_in[1];
  const float* nw     = (const float*)d_in[2];
  const float* Wi     = (const float*)d_in[3];
  const float* cw     = (const float*)d_in[4];
  const float* cbi    = (const float*)d_in[5];
  const float* Wx     = (const float*)d_in[6];
  const float* Wdt    = (const float*)d_in[7];
  const float* bdt    = (const float*)d_in[8];
  const float* Alog   = (const float*)d_in[9];
  const float* Dp     = (const float*)d_in[10];
  const float* Wo     = (const float*)d_in[11];
  const float* flw    = (const float*)d_in[12];
  const float* flb    = (const float*)d_in[13];
  const float* blw    = (const float*)d_in[14];
  const float* blb    = (const float*)d_in[15];
  const float* olw    = (const float*)d_in[16];
  const float* olb    = (const float*)d_in[17];
  float* outp = (float*)d_out;

  char* w = (char*)d_ws;
  size_t off = 0;
  auto take = [&](size_t bytes) -> void* {
    char* p = w + off;
    off += (bytes + 255) & ~(size_t)255;
    return (void*)p;
  };
  ushort* Wct  = (ushort*)take((size_t)4 * 768 * DM * 2);
  ushort* Wxt  = (ushort*)take((size_t)4 * 64 * DI * 2);
  ushort* Wot  = (ushort*)take((size_t)4 * DM * DI * 2);
  ushort* xon  = (ushort*)take((size_t)2 * LSEQ * DM * 2);   // per order
  ushort* xc   = (ushort*)take((size_t)2 * LSEQ * DI * 2);   // per dir (z)
  ushort* zc   = (ushort*)take((size_t)2 * LSEQ * DI * 2);
  ushort* uc   = (ushort*)take((size_t)2 * LSEQ * DI * 2);
  ushort* ybuf = (ushort*)take((size_t)2 * LSEQ * DI * 2);
  float*  proj = (float*) take((size_t)2 * LSEQ * NPROJ * 4);
  ushort* g4   = (ushort*)take((size_t)2 * LSEQ * DM * 2);   // z=0 fwd, z=1 bwd
  float*  Pc   = (float*) take((size_t)2 * NCH * GDIM * 4);
  float*  Sc   = (float*) take((size_t)2 * NCH * GDIM * 4);
  float*  Hc   = (float*) take((size_t)2 * NCH * GDIM * 4);
  float*  PL   = (float*) take((size_t)2 * NGRP * GDIM * 4);
  float*  SL   = (float*) take((size_t)2 * NGRP * GDIM * 4);
  float*  HL   = (float*) take((size_t)2 * NGRP * GDIM * 4);
  (void)ws_size; (void)n_in; (void)in_sizes; (void)out_size;

  // weight prep, all 4 blocks, once
  k_prep<<<(PREP_A + PREP_B + PREP_C + 255)/256, 256, 0, stream>>>(
      Wi, nw, Wx, Wo, Wct, Wxt, Wot);
  // gather+rms for both orders
  k_gather_rms<<<dim3(LSEQ, 2), 64, 0, stream>>>(x, orders, xon);

  for (int o = 0; o < 2; o++) {
    const int* idx = orders + (size_t)o * LSEQ;

    // in-proj (z=dir): xc/zc(bf16, ld 384) = xon[o] @ Wc[blk]
    k_mm<4,0,2><<<dim3(768/64, LSEQ/128, 2), 256, 0, stream>>>(
        xon + (size_t)o*LSEQ*DM, nullptr, nullptr, Wct + (size_t)o*768*DM,
        xc, zc, 768, DM, DM, 0, 384,
        0L, 0L, 0L, (long)2*768*DM, (long)LSEQ*DI);
    // conv (z=dir)
    k_conv<<<dim3((LSEQ*DI + 255)/256, 2), 256, 0, stream>>>(xc, cw, cbi, uc, o);
    // x-proj (z=dir): proj(f32, ld 44) = uc @ Wx
    k_mm<2,0,0><<<dim3(1, LSEQ/64, 2), 256, 0, stream>>>(
        uc, nullptr, nullptr, Wxt + (size_t)o*64*DI,
        proj, nullptr, NPROJ, DI, DI, 0, NPROJ,
        (long)LSEQ*DI, 0L, 0L, (long)2*64*DI, (long)LSEQ*NPROJ);
    // scans (dt fused, z=dir)
    k_scan1<<<dim3(DI/128, NCH, 2), 128, 0, stream>>>(
        uc, proj, Alog, Wdt, bdt, Pc, Sc, o);
    k_scan2a<<<dim3(GDIM/256, NGRP, 2), 256, 0, stream>>>(Pc, Sc, PL, SL);
    k_scan2b<<<dim3(GDIM/256, 2), 256, 0, stream>>>(PL, SL, HL);
    k_scan2c<<<dim3(GDIM/256, NGRP, 2), 256, 0, stream>>>(Pc, Sc, HL, Hc);
    k_scan3<<<dim3(DI/128, NCH, 2), 128, 0, stream>>>(
        uc, proj, Alog, Wdt, bdt, Dp, Hc, ybuf, o);
    // out-proj (z=dir): g4(bf16, ld 192) = (y * silu(z)) @ Wo
    k_mm<2,1,1><<<dim3(DM/64, LSEQ/64, 2), 256, 0, stream>>>(
        nullptr, ybuf, zc, Wot + (size_t)o*DM*DI,
        g4, nullptr, DM, DI, DI, DI, DM,
        0L, (long)LSEQ*DI, (long)LSEQ*DI, (long)2*DM*DI, (long)LSEQ*DM);

    if (o == 0)
      k_final<1><<<LSEQ, 64, 0, stream>>>(x, idx, g4, g4 + (size_t)LSEQ*DM,
          flw, flb, blw, blb, olw, olb, outp);
    else
      k_final<0><<<LSEQ, 64, 0, stream>>>(x, idx, g4, g4 + (size_t)LSEQ*DM,
          flw + (size_t)DM, flb + (size_t)DM,
          blw + (size_t)DM, blb + (size_t)DM,
          olw + (size_t)DM, olb + (size_t)DM, outp);
  }
}

// Round 6
// 514.815 us; speedup vs baseline: 3.0299x; 1.0424x over previous
//
#include <hip/hip_runtime.h>
#include <math.h>

#define LSEQ 16384
#define DM 192
#define DI 384
#define DSN 16
#define DCONV 4
#define DTRK 12
#define NPROJ 44   /* DTRK + 2*DSN */
#define EPSV 1e-5f
#define TCH 32
#define NCH (LSEQ / TCH)          /* 512 chunks */
#define GDIM (DI * DSN)           /* 6144 sequences */
#define RGRP 8                    /* chunks per group */
#define NGRP (NCH / RGRP)         /* 64 groups */

typedef __attribute__((ext_vector_type(8))) short bf16x8;
typedef __attribute__((ext_vector_type(4))) float f32x4;

__device__ __forceinline__ float siluf(float x) { return x / (1.f + __expf(-x)); }
__device__ __forceinline__ float softplus_f(float x) {
  float e = __expf(x);
  float l = __logf(1.f + e);
  return (x > 20.f) ? x : l;
}
__device__ __forceinline__ ushort f2b(float f) {
  uint u = __float_as_uint(f);
  u += 0x7fff + ((u >> 16) & 1);
  return (ushort)(u >> 16);
}
__device__ __forceinline__ float b2f(ushort h) { return __uint_as_float(((uint)h) << 16); }

// a[n] = q^(n+1), log-depth
__device__ __forceinline__ void pow16(float q, float (&a)[16]) {
  float q2 = q*q, q4 = q2*q2, q8 = q4*q4;
  a[0]=q;        a[1]=q2;       a[2]=q2*q;      a[3]=q4;
  a[4]=q4*q;     a[5]=q4*q2;    a[6]=q4*q2*q;   a[7]=q8;
  a[8]=q8*q;     a[9]=q8*q2;    a[10]=q8*q2*q;  a[11]=q8*q4;
  a[12]=q8*q4*q; a[13]=q8*q4*q2;a[14]=q8*q4*q2*q;a[15]=q8*q8;
}

// ---------------- unified weight prep (all 4 blocks) ----------------
#define PREP_A (4 * 768 * DM)
#define PREP_B (4 * 64 * DI)
#define PREP_C (4 * DM * DI)
__global__ void k_prep(const float* __restrict__ Wi, const float* __restrict__ nw,
                       const float* __restrict__ Wx, const float* __restrict__ Wo,
                       ushort* __restrict__ Wct, ushort* __restrict__ Wxt,
                       ushort* __restrict__ Wot) {
  int i = blockIdx.x * 256 + threadIdx.x;
  if (i < PREP_A) {
    int blk = i / (768 * DM), j = i % (768 * DM);
    int n = j / DM, k = j % DM;
    Wct[i] = f2b(nw[blk*DM + k] * Wi[(size_t)blk*DM*768 + (size_t)k*768 + n]);
  } else if (i < PREP_A + PREP_B) {
    int q = i - PREP_A;
    int blk = q / (64 * DI), j = q % (64 * DI);
    int n = j / DI, k = j % DI;
    Wxt[q] = (n < NPROJ) ? f2b(Wx[(size_t)blk*DI*NPROJ + (size_t)k*NPROJ + n]) : (ushort)0;
  } else if (i < PREP_A + PREP_B + PREP_C) {
    int q = i - PREP_A - PREP_B;
    int blk = q / (DM * DI), j = q % (DM * DI);
    int n = j / DI, k = j % DI;
    Wot[q] = f2b(Wo[(size_t)blk*DI*DM + (size_t)k*DM + n]);
  }
}

// ---------------- gather + rmsnorm -> bf16 (both orders, z = order) ----------------
__global__ __launch_bounds__(64) void k_gather_rms(const float* __restrict__ x,
                                                   const int* __restrict__ orders,
                                                   ushort* __restrict__ xon) {
  int t = blockIdx.x;
  int o = blockIdx.y;
  int lane = threadIdx.x;
  int r = orders[(size_t)o*LSEQ + t];
  ushort* xo = xon + (size_t)o*LSEQ*DM;
  float v0 = x[(size_t)r*DM + lane];
  float v1 = x[(size_t)r*DM + 64 + lane];
  float v2 = x[(size_t)r*DM + 128 + lane];
  float ss = v0*v0 + v1*v1 + v2*v2;
  #pragma unroll
  for (int oo = 32; oo > 0; oo >>= 1) ss += __shfl_xor(ss, oo);
  float s = rsqrtf(ss * (1.f/DM) + EPSV);
  xo[(size_t)t*DM + lane]       = f2b(v0 * s);
  xo[(size_t)t*DM + 64 + lane]  = f2b(v1 * s);
  xo[(size_t)t*DM + 128 + lane] = f2b(v2 * s);
}

// ---------------- MFMA GEMM, z-batched. blockIdx.x = M-tile (L2 reuse), y = N-tile ----------------
// AMODE 0: A bf16 (lda). AMODE 1: A[m][k] = b2f(Y)*silu(b2f(Z)).
// AMODE 2: A[m][k] = silu(conv(XC)[m][k]) — causal depthwise conv along m, dir from z.
// OMODE 0: f32 out (C0). OMODE 1: bf16 out (C0). OMODE 2: bf16 split at col 384 (C0/C1, ld 384).
template<int MI, int AMODE, int OMODE>
__global__ __launch_bounds__(256) void k_mm(
    const ushort* __restrict__ A, const ushort* __restrict__ Yp,
    const ushort* __restrict__ Zp, const ushort* __restrict__ Bt,
    const float* __restrict__ cw, const float* __restrict__ cb, int o,
    void* __restrict__ C0, void* __restrict__ C1,
    int N, int K, int lda, int ldz, int ldc,
    long sA, long sY, long sZ, long sB, long sC)
{
  __shared__ __align__(16) ushort As[32 * MI * 64];
  __shared__ __align__(16) ushort Bs[64 * 64];
  const int z = blockIdx.z;
  const int sgn = 1 - 2*z;
  if (AMODE != 1) A += (size_t)z * sA;
  else { Yp += (size_t)z * sY; Zp += (size_t)z * sZ; }
  Bt += (size_t)z * sB;
  const int bm = blockIdx.x * (32 * MI), bn = blockIdx.y * 64;
  const int tid = threadIdx.x;
  const int l = tid & 63, w = tid >> 6;
  const int wm = w & 1, wn = w >> 1;
  f32x4 acc[MI][2] = {};

  for (int k0 = 0; k0 < K; k0 += 64) {
    #pragma unroll
    for (int p = 0; p < MI; p++) {
      int c = tid + p * 256;
      int row = c >> 3, ko = (c & 7) * 8;
      int sw = (row * 128 + (c & 7) * 16) ^ ((row & 7) << 4);
      if (AMODE == 0) {
        uint4 v = *(const uint4*)(A + (size_t)(bm + row) * lda + k0 + ko);
        *(uint4*)((char*)As + sw) = v;
      } else if (AMODE == 1) {
        const ushort* yrow = Yp + (size_t)(bm + row) * lda + k0 + ko;
        const ushort* zrow = Zp + (size_t)(bm + row) * ldz + k0 + ko;
        ushort tmp[8];
        #pragma unroll
        for (int j = 0; j < 8; j++) {
          float zz = b2f(zrow[j]);
          tmp[j] = f2b(b2f(yrow[j]) * (zz / (1.f + __expf(-zz))));
        }
        *(uint4*)((char*)As + sw) = *(const uint4*)tmp;
      } else {
        // conv+silu staging: output row m = bm+row, cols k0+ko..+7 (d-dims)
        int m = bm + row;
        int blk = o + 2*z;
        int dbase = k0 + ko;
        float accv[8];
        #pragma unroll
        for (int j = 0; j < 8; j++) accv[j] = cb[blk*DI + dbase + j];
        #pragma unroll
        for (int k = 0; k < DCONV; k++) {
          int r = (sgn > 0) ? (m - (DCONV-1) + k) : (m + (DCONV-1) - k);
          if (r >= 0 && r < LSEQ) {
            uint4 xv = *(const uint4*)(A + (size_t)r*DI + dbase);
            const ushort* xs = (const ushort*)&xv;
            #pragma unroll
            for (int j = 0; j < 8; j++)
              accv[j] = fmaf(cw[(size_t)blk*DI*DCONV + (dbase+j)*DCONV + k],
                             b2f(xs[j]), accv[j]);
          }
        }
        ushort tmp[8];
        #pragma unroll
        for (int j = 0; j < 8; j++) tmp[j] = f2b(siluf(accv[j]));
        *(uint4*)((char*)As + sw) = *(const uint4*)tmp;
      }
    }
    #pragma unroll
    for (int p = 0; p < 2; p++) {
      int c = tid + p * 256;
      int row = c >> 3, ko = (c & 7) * 8;
      int sw = (row * 128 + (c & 7) * 16) ^ ((row & 7) << 4);
      uint4 v = *(const uint4*)(Bt + (size_t)(bn + row) * K + k0 + ko);
      *(uint4*)((char*)Bs + sw) = v;
    }
    __syncthreads();
    #pragma unroll
    for (int ks = 0; ks < 2; ks++) {
      bf16x8 af[MI], bfv[2];
      #pragma unroll
      for (int mi = 0; mi < MI; mi++) {
        int r = 16 * MI * wm + 16 * mi + (l & 15);
        int ad = (r * 128 + 32 * ks + 16 * (l >> 4)) ^ ((r & 7) << 4);
        af[mi] = *(const bf16x8*)((const char*)As + ad);
      }
      #pragma unroll
      for (int ni = 0; ni < 2; ni++) {
        int r = 32 * wn + 16 * ni + (l & 15);
        int ad = (r * 128 + 32 * ks + 16 * (l >> 4)) ^ ((r & 7) << 4);
        bfv[ni] = *(const bf16x8*)((const char*)Bs + ad);
      }
      #pragma unroll
      for (int mi = 0; mi < MI; mi++)
        #pragma unroll
        for (int ni = 0; ni < 2; ni++)
          acc[mi][ni] = __builtin_amdgcn_mfma_f32_16x16x32_bf16(
              af[mi], bfv[ni], acc[mi][ni], 0, 0, 0);
    }
    __syncthreads();
  }

  #pragma unroll
  for (int mi = 0; mi < MI; mi++) {
    #pragma unroll
    for (int ni = 0; ni < 2; ni++) {
      int c0 = bn + 32 * wn + 16 * ni + (l & 15);
      if (OMODE != 2 && c0 >= N) continue;
      int r0 = bm + 16 * MI * wm + 16 * mi + 4 * (l >> 4);
      #pragma unroll
      for (int j = 0; j < 4; j++) {
        if (OMODE == 0) {
          ((float*)C0 + (size_t)z*sC)[(size_t)(r0 + j) * ldc + c0] = acc[mi][ni][j];
        } else if (OMODE == 1) {
          ((ushort*)C0 + (size_t)z*sC)[(size_t)(r0 + j) * ldc + c0] = f2b(acc[mi][ni][j]);
        } else {
          if (c0 < 384)
            ((ushort*)C0 + (size_t)z*sC)[(size_t)(r0 + j) * 384 + c0] = f2b(acc[mi][ni][j]);
          else
            ((ushort*)C1 + (size_t)z*sC)[(size_t)(r0 + j) * 384 + (c0 - 384)] = f2b(acc[mi][ni][j]);
        }
      }
    }
  }
}

// ---------------- scan phase 1 (conv fused), z = dir ----------------
__global__ __launch_bounds__(128) void k_scan1(const ushort* __restrict__ XC,
                                               const float* __restrict__ PROJ,
                                               const float* __restrict__ Alog,
                                               const float* __restrict__ Wdt,
                                               const float* __restrict__ bdt,
                                               const float* __restrict__ cw,
                                               const float* __restrict__ cb,
                                               float* __restrict__ Pc,
                                               float* __restrict__ Sc, int o) {
  __shared__ float Ps[TCH][NPROJ];
  __shared__ ushort Xs[TCH+3][128];
  int z = blockIdx.z;
  int blk = o + 2*z;
  int sgn = 1 - 2*z;
  const ushort* Xz = XC + (size_t)z*LSEQ*DI;
  const float* Pz = PROJ + (size_t)z*LSEQ*NPROJ;
  int c = blockIdx.y;
  int dd = blockIdx.x * 128;
  int tid = threadIdx.x;
  int d = dd + tid;
  for (int j = tid; j < TCH * 11; j += 128) {
    int row = j / 11, q4 = j % 11;
    int s = c*TCH + row;
    int rg = (sgn > 0) ? s : (LSEQ-1-s);
    *(float4*)&Ps[row][q4*4] = *(const float4*)(Pz + (size_t)rg*NPROJ + q4*4);
  }
  int base = (sgn > 0) ? (c*TCH - 3) : (LSEQ - (c+1)*TCH);
  for (int j = tid; j < (TCH+3)*16; j += 128) {
    int row = j >> 4, v = j & 15;
    int r = base + row;
    uint4 val = {0,0,0,0};
    if (r >= 0 && r < LSEQ) val = *(const uint4*)(Xz + (size_t)r*DI + dd + v*8);
    *(uint4*)&Xs[row][v*8] = val;
  }
  __syncthreads();

  float4 wv = *(const float4*)(cw + (size_t)blk*DI*DCONV + d*DCONV);
  float cbv = cb[blk*DI + d];
  float wdt[DTRK];
  #pragma unroll
  for (int k = 0; k < DTRK; k++) wdt[k] = Wdt[(size_t)blk*DTRK*DI + k*DI + d];
  float bdtv = bdt[blk*DI + d];
  float A[DSN]; bool fast = true;
  #pragma unroll
  for (int n = 0; n < DSN; n++) {
    A[n] = -__expf(Alog[(size_t)blk*DI*DSN + d*DSN + n]);
    fast = fast && (fabsf(A[n] + (float)(n+1)) <= 1e-3f * (n+1));
  }
  float S[DSN] = {};
  float dtsum = 0.f;
  for (int t = 0; t < TCH; t++) {
    float accv = cbv;
    #pragma unroll
    for (int k = 0; k < DCONV; k++) {
      int wc = (sgn > 0) ? (t + k) : (TCH + 2 - t - k);
      accv = fmaf(((const float*)&wv)[k], b2f(Xs[wc][tid]), accv);
    }
    float u = siluf(accv);
    float xdt = bdtv;
    #pragma unroll
    for (int k = 0; k < DTRK; k++) xdt += Ps[t][k] * wdt[k];
    float dtv = softplus_f(xdt);
    float du = dtv * u;
    dtsum += dtv;
    float a[DSN];
    if (fast) { pow16(__expf(-dtv), a); }
    else {
      #pragma unroll
      for (int n = 0; n < DSN; n++) a[n] = __expf(dtv * A[n]);
    }
    #pragma unroll
    for (int n = 0; n < DSN; n++)
      S[n] = a[n] * S[n] + du * Ps[t][DTRK + n];
  }
  float P[DSN];
  if (fast) { pow16(__expf(-dtsum), P); }
  else {
    #pragma unroll
    for (int n = 0; n < DSN; n++) P[n] = __expf(A[n] * dtsum);
  }
  size_t bo = (size_t)z*NCH*GDIM + (size_t)c * GDIM + (size_t)d * DSN;
  #pragma unroll
  for (int q = 0; q < 4; q++) {
    *(float4*)(Pc + bo + q*4) = make_float4(P[4*q], P[4*q+1], P[4*q+2], P[4*q+3]);
    *(float4*)(Sc + bo + q*4) = make_float4(S[4*q], S[4*q+1], S[4*q+2], S[4*q+3]);
  }
}

// ---------------- scan 2a ----------------
__global__ __launch_bounds__(256) void k_scan2a(const float* __restrict__ Pc,
                                                const float* __restrict__ Sc,
                                                float* __restrict__ PL,
                                                float* __restrict__ SL) {
  int g = blockIdx.x * 256 + threadIdx.x;
  int l = blockIdx.y;
  int z = blockIdx.z;
  const float* Pz = Pc + (size_t)z*NCH*GDIM;
  const float* Sz = Sc + (size_t)z*NCH*GDIM;
  float Pa = 1.f, Sa = 0.f;
  #pragma unroll
  for (int j = 0; j < RGRP; j++) {
    size_t off = (size_t)(l*RGRP + j) * GDIM + g;
    float p = Pz[off], s = Sz[off];
    Sa = fmaf(p, Sa, s);
    Pa *= p;
  }
  PL[(size_t)z*NGRP*GDIM + (size_t)l * GDIM + g] = Pa;
  SL[(size_t)z*NGRP*GDIM + (size_t)l * GDIM + g] = Sa;
}

// ---------------- scan 2b ----------------
__global__ __launch_bounds__(256) void k_scan2b(const float* __restrict__ PL,
                                                const float* __restrict__ SL,
                                                float* __restrict__ HL) {
  int g = blockIdx.x * 256 + threadIdx.x;
  int z = blockIdx.y;
  const float* Pz = PL + (size_t)z*NGRP*GDIM;
  const float* Sz = SL + (size_t)z*NGRP*GDIM;
  float* Hz = HL + (size_t)z*NGRP*GDIM;
  float p[NGRP], s[NGRP];
  #pragma unroll
  for (int l = 0; l < NGRP; l++) {
    p[l] = Pz[(size_t)l * GDIM + g];
    s[l] = Sz[(size_t)l * GDIM + g];
  }
  float H = 0.f;
  #pragma unroll
  for (int l = 0; l < NGRP; l++) {
    Hz[(size_t)l * GDIM + g] = H;
    H = fmaf(p[l], H, s[l]);
  }
}

// ---------------- scan 2c ----------------
__global__ __launch_bounds__(256) void k_scan2c(const float* __restrict__ Pc,
                                                const float* __restrict__ Sc,
                                                const float* __restrict__ HL,
                                                float* __restrict__ Hc) {
  int g = blockIdx.x * 256 + threadIdx.x;
  int l = blockIdx.y;
  int z = blockIdx.z;
  const float* Pz = Pc + (size_t)z*NCH*GDIM;
  const float* Sz = Sc + (size_t)z*NCH*GDIM;
  float h = HL[(size_t)z*NGRP*GDIM + (size_t)l * GDIM + g];
  float* Hz = Hc + (size_t)z*NCH*GDIM;
  #pragma unroll
  for (int j = 0; j < RGRP; j++) {
    size_t off = (size_t)(l*RGRP + j) * GDIM + g;
    Hz[off] = h;
    h = fmaf(Pz[off], h, Sz[off]);
  }
}

// ---------------- scan phase 3 (conv fused), z = dir ----------------
__global__ __launch_bounds__(128) void k_scan3(const ushort* __restrict__ XC,
                                               const float* __restrict__ PROJ,
                                               const float* __restrict__ Alog,
                                               const float* __restrict__ Wdt,
                                               const float* __restrict__ bdt,
                                               const float* __restrict__ cw,
                                               const float* __restrict__ cb,
                                               const float* __restrict__ Dp,
                                               const float* __restrict__ Hc,
                                               ushort* __restrict__ Y, int o) {
  __shared__ float Ps[TCH][NPROJ];
  __shared__ ushort Xs[TCH+3][128];
  int z = blockIdx.z;
  int blk = o + 2*z;
  int sgn = 1 - 2*z;
  const ushort* Xz = XC + (size_t)z*LSEQ*DI;
  const float* Pz = PROJ + (size_t)z*LSEQ*NPROJ;
  ushort* Yz = Y + (size_t)z*LSEQ*DI;
  int c = blockIdx.y;
  int dd = blockIdx.x * 128;
  int tid = threadIdx.x;
  int d = dd + tid;
  for (int j = tid; j < TCH * 11; j += 128) {
    int row = j / 11, q4 = j % 11;
    int s = c*TCH + row;
    int rg = (sgn > 0) ? s : (LSEQ-1-s);
    *(float4*)&Ps[row][q4*4] = *(const float4*)(Pz + (size_t)rg*NPROJ + q4*4);
  }
  int base = (sgn > 0) ? (c*TCH - 3) : (LSEQ - (c+1)*TCH);
  for (int j = tid; j < (TCH+3)*16; j += 128) {
    int row = j >> 4, v = j & 15;
    int r = base + row;
    uint4 val = {0,0,0,0};
    if (r >= 0 && r < LSEQ) val = *(const uint4*)(Xz + (size_t)r*DI + dd + v*8);
    *(uint4*)&Xs[row][v*8] = val;
  }
  __syncthreads();

  float4 wv = *(const float4*)(cw + (size_t)blk*DI*DCONV + d*DCONV);
  float cbv = cb[blk*DI + d];
  float wdt[DTRK];
  #pragma unroll
  for (int k = 0; k < DTRK; k++) wdt[k] = Wdt[(size_t)blk*DTRK*DI + k*DI + d];
  float bdtv = bdt[blk*DI + d];
  float A[DSN]; bool fast = true;
  #pragma unroll
  for (int n = 0; n < DSN; n++) {
    A[n] = -__expf(Alog[(size_t)blk*DI*DSN + d*DSN + n]);
    fast = fast && (fabsf(A[n] + (float)(n+1)) <= 1e-3f * (n+1));
  }
  float h[DSN];
  size_t hb = (size_t)z*NCH*GDIM + (size_t)c * GDIM + (size_t)d * DSN;
  #pragma unroll
  for (int q = 0; q < 4; q++) {
    float4 hv = *(const float4*)(Hc + hb + q*4);
    h[4*q] = hv.x; h[4*q+1] = hv.y; h[4*q+2] = hv.z; h[4*q+3] = hv.w;
  }
  float dskip = Dp[blk*DI + d];

  for (int t = 0; t < TCH; t++) {
    int s = c*TCH + t;
    int row = (sgn > 0) ? s : (LSEQ-1-s);
    float accv = cbv;
    #pragma unroll
    for (int k = 0; k < DCONV; k++) {
      int wc = (sgn > 0) ? (t + k) : (TCH + 2 - t - k);
      accv = fmaf(((const float*)&wv)[k], b2f(Xs[wc][tid]), accv);
    }
    float u = siluf(accv);
    float xdt = bdtv;
    #pragma unroll
    for (int k = 0; k < DTRK; k++) xdt += Ps[t][k] * wdt[k];
    float dtv = softplus_f(xdt);
    float du = dtv * u;
    float a[DSN];
    if (fast) { pow16(__expf(-dtv), a); }
    else {
      #pragma unroll
      for (int n = 0; n < DSN; n++) a[n] = __expf(dtv * A[n]);
    }
    float y = u * dskip;
    #pragma unroll
    for (int n = 0; n < DSN; n++) {
      h[n] = a[n] * h[n] + du * Ps[t][DTRK + n];
      y += h[n] * Ps[t][DTRK + DSN + n];
    }
    Yz[(size_t)row * DI + d] = f2b(y);
  }
}

// ---------------- final combine ----------------
__device__ __forceinline__ void ln_row(float (&v)[3], const float* __restrict__ w,
                                       const float* __restrict__ b, int lane) {
  float s = v[0] + v[1] + v[2];
  #pragma unroll
  for (int o = 32; o > 0; o >>= 1) s += __shfl_xor(s, o);
  float m = s * (1.f / DM);
  float q = 0.f;
  #pragma unroll
  for (int i = 0; i < 3; i++) { float d = v[i] - m; q += d*d; }
  #pragma unroll
  for (int o = 32; o > 0; o >>= 1) q += __shfl_xor(q, o);
  float inv = rsqrtf(q * (1.f / DM) + EPSV);
  #pragma unroll
  for (int i = 0; i < 3; i++) v[i] = (v[i] - m) * inv * w[lane + 64*i] + b[lane + 64*i];
}

// FIRST=1: out = x + cb (idx is a permutation). FIRST=0: out += cb.
template<int FIRST>
__global__ __launch_bounds__(64) void k_final(const float* __restrict__ x,
                                              const int* __restrict__ idx,
                                              const ushort* __restrict__ G4f,
                                              const ushort* __restrict__ G4b,
                                              const float* __restrict__ lnfw,
                                              const float* __restrict__ lnfb,
                                              const float* __restrict__ lnbw,
                                              const float* __restrict__ lnbb,
                                              const float* __restrict__ lnow,
                                              const float* __restrict__ lnob,
                                              float* __restrict__ out) {
  int t = blockIdx.x, lane = threadIdx.x;
  int r = idx[t];
  float f[3], g[3], cb[3];
  #pragma unroll
  for (int i = 0; i < 3; i++) {
    int j = lane + 64*i;
    float xo = x[(size_t)r*DM + j];
    f[i] = xo + b2f(G4f[(size_t)t*DM + j]);
    g[i] = xo + b2f(G4b[(size_t)t*DM + j]);
  }
  ln_row(f, lnfw, lnfb, lane);
  ln_row(g, lnbw, lnbb, lane);
  #pragma unroll
  for (int i = 0; i < 3; i++) cb[i] = f[i] + g[i];
  ln_row(cb, lnow, lnob, lane);
  #pragma unroll
  for (int i = 0; i < 3; i++) {
    int j = lane + 64*i;
    if (FIRST)
      out[(size_t)r*DM + j] = x[(size_t)r*DM + j] + cb[i];
    else
      out[(size_t)r*DM + j] += cb[i];
  }
}

extern "C" void kernel_launch(void* const* d_in, const int* in_sizes, int n_in,
                              void* d_out, int out_size, void* d_ws, size_t ws_size,
                              hipStream_t stream) {
  const float* x      = (const float*)d_in[0];
  const int*   orders = (const int*)  d_in[1];
  const float* nw     = (const float*)d_in[2];
  const float* Wi     = (const float*)d_in[3];
  const float* cw     = (const float*)d_in[4];
  const float* cbi    = (const float*)d_in[5];
  const float* Wx     = (const float*)d_in[6];
  const float* Wdt    = (const float*)d_in[7];
  const float* bdt    = (const float*)d_in[8];
  const float* Alog   = (const float*)d_in[9];
  const float* Dp     = (const float*)d_in[10];
  const float* Wo     = (const float*)d_in[11];
  const float* flw    = (const float*)d_in[12];
  const float* flb    = (const float*)d_in[13];
  const float* blw    = (const float*)d_in[14];
  const float* blb    = (const float*)d_in[15];
  const float* olw    = (const float*)d_in[16];
  const float* olb    = (const float*)d_in[17];
  float* outp = (float*)d_out;

  char* w = (char*)d_ws;
  size_t off = 0;
  auto take = [&](size_t bytes) -> void* {
    char* p = w + off;
    off += (bytes + 255) & ~(size_t)255;
    return (void*)p;
  };
  ushort* Wct  = (ushort*)take((size_t)4 * 768 * DM * 2);
  ushort* Wxt  = (ushort*)take((size_t)4 * 64 * DI * 2);
  ushort* Wot  = (ushort*)take((size_t)4 * DM * DI * 2);
  ushort* xon  = (ushort*)take((size_t)2 * LSEQ * DM * 2);   // per order
  ushort* xc   = (ushort*)take((size_t)2 * LSEQ * DI * 2);   // per dir (z)
  ushort* zc   = (ushort*)take((size_t)2 * LSEQ * DI * 2);
  ushort* ybuf = (ushort*)take((size_t)2 * LSEQ * DI * 2);
  float*  proj = (float*) take((size_t)2 * LSEQ * NPROJ * 4);
  ushort* g4   = (ushort*)take((size_t)2 * LSEQ * DM * 2);   // z=0 fwd, z=1 bwd
  float*  Pc   = (float*) take((size_t)2 * NCH * GDIM * 4);
  float*  Sc   = (float*) take((size_t)2 * NCH * GDIM * 4);
  float*  Hc   = (float*) take((size_t)2 * NCH * GDIM * 4);
  float*  PL   = (float*) take((size_t)2 * NGRP * GDIM * 4);
  float*  SL   = (float*) take((size_t)2 * NGRP * GDIM * 4);
  float*  HL   = (float*) take((size_t)2 * NGRP * GDIM * 4);
  (void)ws_size; (void)n_in; (void)in_sizes; (void)out_size;

  // weight prep, all 4 blocks, once
  k_prep<<<(PREP_A + PREP_B + PREP_C + 255)/256, 256, 0, stream>>>(
      Wi, nw, Wx, Wo, Wct, Wxt, Wot);
  // gather+rms for both orders
  k_gather_rms<<<dim3(LSEQ, 2), 64, 0, stream>>>(x, orders, xon);

  for (int o = 0; o < 2; o++) {
    const int* idx = orders + (size_t)o * LSEQ;

    // in-proj (z=dir): xc/zc(bf16, ld 384) = xon[o] @ Wc[blk]
    k_mm<4,0,2><<<dim3(LSEQ/128, 768/64, 2), 256, 0, stream>>>(
        xon + (size_t)o*LSEQ*DM, nullptr, nullptr, Wct + (size_t)o*768*DM,
        nullptr, nullptr, o, xc, zc, 768, DM, DM, 0, 384,
        0L, 0L, 0L, (long)2*768*DM, (long)LSEQ*DI);
    // x-proj (z=dir): proj(f32, ld 44) = silu(conv(xc)) @ Wx  (conv fused in A-stage)
    k_mm<2,2,0><<<dim3(LSEQ/64, 1, 2), 256, 0, stream>>>(
        xc, nullptr, nullptr, Wxt + (size_t)o*64*DI,
        cw, cbi, o, proj, nullptr, NPROJ, DI, DI, 0, NPROJ,
        (long)LSEQ*DI, 0L, 0L, (long)2*64*DI, (long)LSEQ*NPROJ);
    // scans (conv+dt fused, z=dir)
    k_scan1<<<dim3(DI/128, NCH, 2), 128, 0, stream>>>(
        xc, proj, Alog, Wdt, bdt, cw, cbi, Pc, Sc, o);
    k_scan2a<<<dim3(GDIM/256, NGRP, 2), 256, 0, stream>>>(Pc, Sc, PL, SL);
    k_scan2b<<<dim3(GDIM/256, 2), 256, 0, stream>>>(PL, SL, HL);
    k_scan2c<<<dim3(GDIM/256, NGRP, 2), 256, 0, stream>>>(Pc, Sc, HL, Hc);
    k_scan3<<<dim3(DI/128, NCH, 2), 128, 0, stream>>>(
        xc, proj, Alog, Wdt, bdt, cw, cbi, Dp, Hc, ybuf, o);
    // out-proj (z=dir): g4(bf16, ld 192) = (y * silu(z)) @ Wo
    k_mm<2,1,1><<<dim3(LSEQ/64, DM/64, 2), 256, 0, stream>>>(
        nullptr, ybuf, zc, Wot + (size_t)o*DM*DI,
        nullptr, nullptr, o, g4, nullptr, DM, DI, DI, DI, DM,
        0L, (long)LSEQ*DI, (long)LSEQ*DI, (long)2*DM*DI, (long)LSEQ*DM);

    if (o == 0)
      k_final<1><<<LSEQ, 64, 0, stream>>>(x, idx, g4, g4 + (size_t)LSEQ*DM,
          flw, flb, blw, blb, olw, olb, outp);
    else
      k_final<0><<<LSEQ, 64, 0, stream>>>(x, idx, g4, g4 + (size_t)LSEQ*DM,
          flw + (size_t)DM, flb + (size_t)DM,
          blw + (size_t)DM, blb + (size_t)DM,
          olw + (size_t)DM, olb + (size_t)DM, outp);
  }
}